// Round 12
// baseline (815.446 us; speedup 1.0000x reference)
//
#include <hip/hip_runtime.h>
#include <hip/hip_bf16.h>
#include <cfloat>

// Problem constants
#define BB 8
#define TT 2048
#define CC 512
#define NNODE 1024

#define GAP_MARGIN 2e-4f  // screening margin (~40 sigma of bf16-split screen noise)
#define MAXC 6            // max rival candidates per flagged token (fits 8-slot clist)
#define NSLOT 64          // recheck flag slots
#define NCHUNK 8          // recheck token chunks (8 x 256 = 2048)

typedef float f32x4 __attribute__((ext_vector_type(4)));
typedef short bf16x8 __attribute__((ext_vector_type(8)));
typedef float float4v __attribute__((ext_vector_type(4)));

// ---------------------------------------------------------------------------
// Order-preserving f32 <-> u32 key
// ---------------------------------------------------------------------------
__device__ __forceinline__ unsigned fkey(float v) {
  unsigned u = __float_as_uint(v);
  return (u & 0x80000000u) ? ~u : (u | 0x80000000u);
}
__device__ __forceinline__ float fdec(unsigned k) {
  unsigned u = (k & 0x80000000u) ? (k & 0x7FFFFFFFu) : ~k;
  return __uint_as_float(u);
}

// bf16 round-to-nearest-even helpers (bit-level)
__device__ __forceinline__ unsigned short bf16_rn(float f) {
  unsigned u = __float_as_uint(f);
  u += 0x7FFFu + ((u >> 16) & 1u);
  return (unsigned short)(u >> 16);
}
__device__ __forceinline__ float bf16_tof(unsigned short h) {
  return __uint_as_float(((unsigned)h) << 16);
}

// ---------------------------------------------------------------------------
// MFMA GEMM: C[m,n] = alpha*sum_k A[m,k]*B(k,n) (+bias), f32 in/out.
//   SPLIT: bf16-split (hh+hl+lh); TRANS_B: B is [N][K] row-major.
// 128x128 tile, BK=32, 256 threads (4 waves, 2x2), 16x16x32 frags.
// ---------------------------------------------------------------------------
template <bool SPLIT, bool TRANS_B, int BIAS_MODE>
__global__ __launch_bounds__(256) void mfma_gemm(
    const float* __restrict__ A, const float* __restrict__ Bm,
    float* __restrict__ Cp, const float* __restrict__ bias,
    int K, int lda, int ldb, int ldc,
    long long sA, long long sB, long long sC, float alpha) {
  __shared__ unsigned short Ah[128][40], Al[128][40], Bh[128][40], Bl[128][40];

  const int b = blockIdx.z;
  A += (long long)b * sA;
  Bm += (long long)b * sB;
  const int m0 = blockIdx.y * 128;
  const int n0 = blockIdx.x * 128;
  const int tid = threadIdx.x;
  const int l = tid & 63;
  const int wid = tid >> 6;
  const int wy = wid >> 1, wx = wid & 1;
  const int lrow = l & 15, lkb = (l >> 4) * 8;

  f32x4 acc[4][4] = {};

  for (int k0 = 0; k0 < K; k0 += 32) {
    {
      int r = tid >> 3, c = (tid & 7) * 4;
#pragma unroll
      for (int p = 0; p < 4; ++p, r += 32) {
        float4v v = *(const float4v*)(A + (long long)(m0 + r) * lda + k0 + c);
#pragma unroll
        for (int i = 0; i < 4; ++i) {
          unsigned short h = bf16_rn(v[i]);
          Ah[r][c + i] = h;
          if (SPLIT) Al[r][c + i] = bf16_rn(v[i] - bf16_tof(h));
        }
      }
    }
    if (TRANS_B) {
      int r = tid >> 3, c = (tid & 7) * 4;
#pragma unroll
      for (int p = 0; p < 4; ++p, r += 32) {
        float4v v = *(const float4v*)(Bm + (long long)(n0 + r) * ldb + k0 + c);
#pragma unroll
        for (int i = 0; i < 4; ++i) {
          unsigned short h = bf16_rn(v[i]);
          Bh[r][c + i] = h;
          if (SPLIT) Bl[r][c + i] = bf16_rn(v[i] - bf16_tof(h));
        }
      }
    } else {
      int kk = tid >> 5, c = (tid & 31) * 4;
#pragma unroll
      for (int p = 0; p < 4; ++p, kk += 8) {
        float4v v = *(const float4v*)(Bm + (long long)(k0 + kk) * ldb + n0 + c);
#pragma unroll
        for (int i = 0; i < 4; ++i) {
          unsigned short h = bf16_rn(v[i]);
          Bh[c + i][kk] = h;
          if (SPLIT) Bl[c + i][kk] = bf16_rn(v[i] - bf16_tof(h));
        }
      }
    }
    __syncthreads();

    bf16x8 ah[4], bh[4], al[4], bl[4];
#pragma unroll
    for (int mf = 0; mf < 4; ++mf) {
      ah[mf] = *(const bf16x8*)&Ah[wy * 64 + mf * 16 + lrow][lkb];
      if (SPLIT) al[mf] = *(const bf16x8*)&Al[wy * 64 + mf * 16 + lrow][lkb];
    }
#pragma unroll
    for (int nf = 0; nf < 4; ++nf) {
      bh[nf] = *(const bf16x8*)&Bh[wx * 64 + nf * 16 + lrow][lkb];
      if (SPLIT) bl[nf] = *(const bf16x8*)&Bl[wx * 64 + nf * 16 + lrow][lkb];
    }
#pragma unroll
    for (int mf = 0; mf < 4; ++mf)
#pragma unroll
      for (int nf = 0; nf < 4; ++nf) {
        acc[mf][nf] =
            __builtin_amdgcn_mfma_f32_16x16x32_bf16(ah[mf], bh[nf], acc[mf][nf], 0, 0, 0);
        if (SPLIT) {
          acc[mf][nf] =
              __builtin_amdgcn_mfma_f32_16x16x32_bf16(ah[mf], bl[nf], acc[mf][nf], 0, 0, 0);
          acc[mf][nf] =
              __builtin_amdgcn_mfma_f32_16x16x32_bf16(al[mf], bh[nf], acc[mf][nf], 0, 0, 0);
        }
      }
    __syncthreads();
  }

#pragma unroll
  for (int mf = 0; mf < 4; ++mf)
#pragma unroll
    for (int r = 0; r < 4; ++r) {
      int m = m0 + wy * 64 + mf * 16 + (l >> 4) * 4 + r;
#pragma unroll
      for (int nf = 0; nf < 4; ++nf) {
        int n = n0 + wx * 64 + nf * 16 + lrow;
        float v = acc[mf][nf][r] * alpha;
        if (BIAS_MODE == 1) v += bias[m];
        if (BIAS_MODE == 2) v += bias[n];
        Cp[sC * b + (long long)m * ldc + n] = v;
      }
    }
}

// ---------------------------------------------------------------------------
// Fused k (bf16-split, f32 out) + v (plain bf16, bf16 out) projection.
// ---------------------------------------------------------------------------
__global__ __launch_bounds__(256) void mfma_kv(
    const float* __restrict__ x, const float* __restrict__ Wk,
    const float* __restrict__ Wv, float* __restrict__ kout,
    unsigned short* __restrict__ vout) {
  __shared__ unsigned short Ah[128][40], Al[128][40], Bkh[128][40], Bkl[128][40],
      Bvh[128][40];

  const int b = blockIdx.z;
  const float* A = x + (size_t)b * TT * CC;
  const int m0 = blockIdx.y * 128;  // tokens
  const int n0 = blockIdx.x * 128;  // out dim
  const int tid = threadIdx.x;
  const int l = tid & 63;
  const int wid = tid >> 6;
  const int wy = wid >> 1, wx = wid & 1;
  const int lrow = l & 15, lkb = (l >> 4) * 8;

  f32x4 acck[4][4] = {}, accv[4][4] = {};

  for (int k0 = 0; k0 < CC; k0 += 32) {
    {
      int r = tid >> 3, c = (tid & 7) * 4;
#pragma unroll
      for (int p = 0; p < 4; ++p, r += 32) {
        float4v v = *(const float4v*)(A + (size_t)(m0 + r) * CC + k0 + c);
        float4v wk = *(const float4v*)(Wk + (size_t)(n0 + r) * CC + k0 + c);
        float4v wv = *(const float4v*)(Wv + (size_t)(n0 + r) * CC + k0 + c);
#pragma unroll
        for (int i = 0; i < 4; ++i) {
          unsigned short h = bf16_rn(v[i]);
          Ah[r][c + i] = h;
          Al[r][c + i] = bf16_rn(v[i] - bf16_tof(h));
          unsigned short hk = bf16_rn(wk[i]);
          Bkh[r][c + i] = hk;
          Bkl[r][c + i] = bf16_rn(wk[i] - bf16_tof(hk));
          Bvh[r][c + i] = bf16_rn(wv[i]);
        }
      }
    }
    __syncthreads();

    bf16x8 ah[4], al[4], bkh[4], bkl[4], bvh[4];
#pragma unroll
    for (int mf = 0; mf < 4; ++mf) {
      ah[mf] = *(const bf16x8*)&Ah[wy * 64 + mf * 16 + lrow][lkb];
      al[mf] = *(const bf16x8*)&Al[wy * 64 + mf * 16 + lrow][lkb];
    }
#pragma unroll
    for (int nf = 0; nf < 4; ++nf) {
      bkh[nf] = *(const bf16x8*)&Bkh[wx * 64 + nf * 16 + lrow][lkb];
      bkl[nf] = *(const bf16x8*)&Bkl[wx * 64 + nf * 16 + lrow][lkb];
      bvh[nf] = *(const bf16x8*)&Bvh[wx * 64 + nf * 16 + lrow][lkb];
    }
#pragma unroll
    for (int mf = 0; mf < 4; ++mf)
#pragma unroll
      for (int nf = 0; nf < 4; ++nf) {
        acck[mf][nf] =
            __builtin_amdgcn_mfma_f32_16x16x32_bf16(ah[mf], bkh[nf], acck[mf][nf], 0, 0, 0);
        acck[mf][nf] =
            __builtin_amdgcn_mfma_f32_16x16x32_bf16(ah[mf], bkl[nf], acck[mf][nf], 0, 0, 0);
        acck[mf][nf] =
            __builtin_amdgcn_mfma_f32_16x16x32_bf16(al[mf], bkh[nf], acck[mf][nf], 0, 0, 0);
        accv[mf][nf] =
            __builtin_amdgcn_mfma_f32_16x16x32_bf16(ah[mf], bvh[nf], accv[mf][nf], 0, 0, 0);
      }
    __syncthreads();
  }

#pragma unroll
  for (int mf = 0; mf < 4; ++mf)
#pragma unroll
    for (int r = 0; r < 4; ++r) {
      int m = m0 + wy * 64 + mf * 16 + (l >> 4) * 4 + r;
#pragma unroll
      for (int nf = 0; nf < 4; ++nf) {
        int n = n0 + wx * 64 + nf * 16 + lrow;
        size_t off = ((size_t)b * TT + m) * CC + n;
        kout[off] = acck[mf][nf][r];
        vout[off] = bf16_rn(accv[mf][nf][r]);
      }
    }
}

// ---------------------------------------------------------------------------
// sim (bf16-split MFMA, no store) + per-block per-token top-3 candidates.
// ---------------------------------------------------------------------------
__global__ __launch_bounds__(256) void mfma_sim_top3(
    const float* __restrict__ q, const float* __restrict__ kb,
    unsigned long long* __restrict__ cand1, unsigned long long* __restrict__ cand2,
    unsigned long long* __restrict__ cand3) {
  __shared__ unsigned short Ah[128][40], Al[128][40], Bh[128][40], Bl[128][40];
  __shared__ unsigned long long c1[128], c2[128], c3[128];

  const int b = blockIdx.z;
  const float* A = q + (size_t)b * NNODE * CC;
  const float* Bm = kb + (size_t)b * TT * CC;
  const int n0 = blockIdx.y * 128;  // nodes
  const int t0 = blockIdx.x * 128;  // tokens
  const int tid = threadIdx.x;
  const int l = tid & 63;
  const int wid = tid >> 6;
  const int wy = wid >> 1, wx = wid & 1;
  const int lrow = l & 15, lkb = (l >> 4) * 8;

  if (tid < 128) { c1[tid] = 0ULL; c2[tid] = 0ULL; c3[tid] = 0ULL; }

  f32x4 acc[4][4] = {};

  for (int k0 = 0; k0 < CC; k0 += 32) {
    {
      int r = tid >> 3, c = (tid & 7) * 4;
#pragma unroll
      for (int p = 0; p < 4; ++p, r += 32) {
        float4v v = *(const float4v*)(A + (size_t)(n0 + r) * CC + k0 + c);
        float4v w = *(const float4v*)(Bm + (size_t)(t0 + r) * CC + k0 + c);
#pragma unroll
        for (int i = 0; i < 4; ++i) {
          unsigned short h = bf16_rn(v[i]);
          Ah[r][c + i] = h;
          Al[r][c + i] = bf16_rn(v[i] - bf16_tof(h));
          unsigned short hb = bf16_rn(w[i]);
          Bh[r][c + i] = hb;
          Bl[r][c + i] = bf16_rn(w[i] - bf16_tof(hb));
        }
      }
    }
    __syncthreads();

    bf16x8 ah[4], al[4], bh[4], bl[4];
#pragma unroll
    for (int mf = 0; mf < 4; ++mf) {
      ah[mf] = *(const bf16x8*)&Ah[wy * 64 + mf * 16 + lrow][lkb];
      al[mf] = *(const bf16x8*)&Al[wy * 64 + mf * 16 + lrow][lkb];
    }
#pragma unroll
    for (int nf = 0; nf < 4; ++nf) {
      bh[nf] = *(const bf16x8*)&Bh[wx * 64 + nf * 16 + lrow][lkb];
      bl[nf] = *(const bf16x8*)&Bl[wx * 64 + nf * 16 + lrow][lkb];
    }
#pragma unroll
    for (int mf = 0; mf < 4; ++mf)
#pragma unroll
      for (int nf = 0; nf < 4; ++nf) {
        acc[mf][nf] =
            __builtin_amdgcn_mfma_f32_16x16x32_bf16(ah[mf], bh[nf], acc[mf][nf], 0, 0, 0);
        acc[mf][nf] =
            __builtin_amdgcn_mfma_f32_16x16x32_bf16(ah[mf], bl[nf], acc[mf][nf], 0, 0, 0);
        acc[mf][nf] =
            __builtin_amdgcn_mfma_f32_16x16x32_bf16(al[mf], bh[nf], acc[mf][nf], 0, 0, 0);
      }
    __syncthreads();
  }

  const float scl = 0.04419417382415922f;
#pragma unroll
  for (int nf = 0; nf < 4; ++nf) {
    int tcol = wx * 64 + nf * 16 + lrow;
    unsigned long long m = 0ULL;
#pragma unroll
    for (int mf = 0; mf < 4; ++mf)
#pragma unroll
      for (int r = 0; r < 4; ++r) {
        unsigned node = (unsigned)(n0 + wy * 64 + mf * 16 + (l >> 4) * 4 + r);
        unsigned long long pk =
            ((unsigned long long)fkey(acc[mf][nf][r] * scl) << 32) | node;
        if (pk > m) m = pk;
      }
    atomicMax(&c1[tcol], m);
  }
  __syncthreads();
#pragma unroll
  for (int nf = 0; nf < 4; ++nf) {
    int tcol = wx * 64 + nf * 16 + lrow;
    unsigned w1 = (unsigned)c1[tcol];
    unsigned long long m = 0ULL;
#pragma unroll
    for (int mf = 0; mf < 4; ++mf)
#pragma unroll
      for (int r = 0; r < 4; ++r) {
        unsigned node = (unsigned)(n0 + wy * 64 + mf * 16 + (l >> 4) * 4 + r);
        if (node == w1) continue;
        unsigned long long pk =
            ((unsigned long long)fkey(acc[mf][nf][r] * scl) << 32) | node;
        if (pk > m) m = pk;
      }
    if (m) atomicMax(&c2[tcol], m);
  }
  __syncthreads();
#pragma unroll
  for (int nf = 0; nf < 4; ++nf) {
    int tcol = wx * 64 + nf * 16 + lrow;
    unsigned w1 = (unsigned)c1[tcol];
    unsigned w2 = (unsigned)c2[tcol];
    unsigned long long m = 0ULL;
#pragma unroll
    for (int mf = 0; mf < 4; ++mf)
#pragma unroll
      for (int r = 0; r < 4; ++r) {
        unsigned node = (unsigned)(n0 + wy * 64 + mf * 16 + (l >> 4) * 4 + r);
        if (node == w1 || node == w2) continue;
        unsigned long long pk =
            ((unsigned long long)fkey(acc[mf][nf][r] * scl) << 32) | node;
        if (pk > m) m = pk;
      }
    if (m) atomicMax(&c3[tcol], m);
  }
  __syncthreads();
  if (tid < 128) {
    size_t base = ((size_t)b * TT + (t0 + tid)) * 8 + blockIdx.y;
    cand1[base] = c1[tid];
    cand2[base] = c2[tid];
    cand3[base] = c3[tid];
  }
}

__global__ __launch_bounds__(256) void fill_zero(unsigned* __restrict__ p, long long n) {
  long long i = (long long)blockIdx.x * 256 + threadIdx.x;
  long long stride = (long long)gridDim.x * 256;
  for (; i < n; i += stride) p[i] = 0u;
}

// 32x32 tile transpose: dst[c][r] = src[r][c], R x C both multiples of 32.
__global__ __launch_bounds__(256) void transpose_kernel(
    const float* __restrict__ src, float* __restrict__ dst, int R, int C) {
  __shared__ float tile[32][33];
  int r0 = blockIdx.y * 32, c0 = blockIdx.x * 32;
  int tx = threadIdx.x & 31, ty = threadIdx.x >> 5;  // 32 x 8
#pragma unroll
  for (int i = 0; i < 4; ++i)
    tile[ty + i * 8][tx] = src[(size_t)(r0 + ty + i * 8) * C + c0 + tx];
  __syncthreads();
#pragma unroll
  for (int i = 0; i < 4; ++i)
    dst[(size_t)(c0 + ty + i * 8) * R + r0 + tx] = tile[tx][ty + i * 8];
}

// ---------------------------------------------------------------------------
// Merge 8x(top-3) -> global top1 + rivals within GAP_MARGIN -> FLAT flag list.
// ---------------------------------------------------------------------------
__global__ __launch_bounds__(256) void merge_flag_kernel(
    const unsigned long long* __restrict__ cand1,
    const unsigned long long* __restrict__ cand2,
    const unsigned long long* __restrict__ cand3,
    unsigned long long* __restrict__ amaxIdx,
    unsigned* __restrict__ gcount, unsigned* __restrict__ gflag,
    unsigned* __restrict__ clist) {
  int bt = blockIdx.x * 256 + threadIdx.x;  // [0, B*T)
  unsigned long long best = 0ULL;
#pragma unroll
  for (int nb = 0; nb < 8; ++nb) {
    unsigned long long v = cand1[(size_t)bt * 8 + nb];
    if (v > best) best = v;
  }
  amaxIdx[bt] = best;
  float v1 = fdec((unsigned)(best >> 32));
  float thr = v1 - GAP_MARGIN;
  unsigned bestnode = (unsigned)best;

  unsigned nodes[MAXC];
  int cnt = 0;
#pragma unroll
  for (int nb = 0; nb < 8; ++nb) {
    unsigned long long cs[3] = {cand1[(size_t)bt * 8 + nb], cand2[(size_t)bt * 8 + nb],
                                cand3[(size_t)bt * 8 + nb]};
#pragma unroll
    for (int s = 0; s < 3; ++s) {
      float v = fdec((unsigned)(cs[s] >> 32));
      unsigned nd = (unsigned)cs[s];
      if (v >= thr && nd != bestnode && cnt < MAXC) nodes[cnt++] = nd;
    }
  }
  if (cnt > 0) {
    unsigned p = atomicAdd(gcount, 1u);
    gflag[p] = (unsigned)bt;
    clist[(size_t)bt * 8] = (unsigned)(cnt + 1);
    clist[(size_t)bt * 8 + 1] = bestnode;
    for (int i = 0; i < cnt; ++i) clist[(size_t)bt * 8 + 2 + i] = nodes[i];
  }
}

// ---------------------------------------------------------------------------
// Exact f64 recheck, COALESCED + CHUNK-PARALLEL, no per-row shuffles.
// Grid: NSLOT x NCHUNK blocks (1D). Block (slot s, chunk ch) handles flags
// fi = s, s+NSLOT, ... ; for each: k64 via WkT (thread-per-d, coalesced),
// z for its 256 tokens via LDS-staged x tiles (thread-per-token), candidate
// partial dots (coalesced Wq) -> f64 atomicAdd into cacc. recheck_final
// argmaxes. Same math as validated round-10 recheck.
// ---------------------------------------------------------------------------
__global__ __launch_bounds__(256) void recheck_partial(
    const float* __restrict__ x, const float* __restrict__ Wq,
    const float* __restrict__ bq, const float* __restrict__ WkT,
    const unsigned* __restrict__ gcount, const unsigned* __restrict__ gflag,
    const unsigned* __restrict__ clist, double* __restrict__ cacc) {
  __shared__ float xs[CC];         // 2 KB
  __shared__ double k64[CC];       // 4 KB
  __shared__ float tile[256][33];  // 33.8 KB
  __shared__ double red[4];

  const unsigned cnt = *gcount;
  const int tid = threadIdx.x;
  const int slot = blockIdx.x >> 3;   // NSLOT slots
  const int chunk = blockIdx.x & 7;   // NCHUNK chunks
  const int tp = chunk * 256 + tid;   // this thread's token

  for (unsigned fi = slot; fi < cnt; fi += NSLOT) {
    unsigned bt = gflag[fi];
    int b = bt >> 11;
    int t = bt & (TT - 1);
    const float* xb = x + (size_t)b * TT * CC;
    for (int c = tid; c < CC; c += 256) xs[c] = xb[(size_t)t * CC + c];
    __syncthreads();

    // k64[d]: thread d and d+256; WkT[c][d] coalesced across lanes
    {
      double a0 = 0.0, a1 = 0.0;
      for (int c = 0; c < CC; ++c) {
        double xv = (double)xs[c];
        a0 = fma((double)WkT[(size_t)c * CC + tid], xv, a0);
        a1 = fma((double)WkT[(size_t)c * CC + tid + 256], xv, a1);
      }
      k64[tid] = a0;
      k64[tid + 256] = a1;
    }
    __syncthreads();

    // ssum = sum(k64), one block-reduce
    double ps = k64[tid] + k64[tid + 256];
#pragma unroll
    for (int off = 32; off > 0; off >>= 1) ps += __shfl_down(ps, off, 64);
    if ((tid & 63) == 0) red[tid >> 6] = ps;
    __syncthreads();
    const double ssum = red[0] + red[1] + red[2] + red[3];

    // z for my token via LDS-staged x tiles (coalesced loads, no shuffles)
    double zacc = 0.0;
    for (int cc = 0; cc < 16; ++cc) {
      __syncthreads();
      int c0 = cc * 32;
#pragma unroll
      for (int j = 0; j < 32; ++j) {
        int lin = j * 256 + tid;
        int row = lin >> 5, col = lin & 31;
        tile[row][col] = xb[(size_t)(chunk * 256 + row) * CC + c0 + col];
      }
      __syncthreads();
#pragma unroll
      for (int j = 0; j < 32; ++j)
        zacc = fma((double)tile[tid][j], k64[c0 + j], zacc);
    }
    __syncthreads();

    // candidate partial dots over this chunk's 256 tokens
    unsigned ncand = clist[(size_t)bt * 8];
    for (unsigned ci = 0; ci < ncand; ++ci) {
      unsigned n = clist[(size_t)bt * 8 + 1 + ci];
      double term = (double)Wq[(size_t)n * TT + tp] * zacc;
#pragma unroll
      for (int off = 32; off > 0; off >>= 1) term += __shfl_down(term, off, 64);
      if ((tid & 63) == 0) red[tid >> 6] = term;
      __syncthreads();
      if (tid == 0) {
        double s = red[0] + red[1] + red[2] + red[3];
        if (chunk == 0) s += (double)bq[n] * ssum;
        atomicAdd(&cacc[(size_t)bt * 8 + ci], s);
      }
      __syncthreads();
    }
    __syncthreads();
  }
}

__global__ __launch_bounds__(256) void recheck_final(
    const unsigned* __restrict__ clist, const double* __restrict__ cacc,
    unsigned long long* __restrict__ amaxIdx) {
  int bt = blockIdx.x * 256 + threadIdx.x;  // [0, B*T)
  unsigned ncand = clist[(size_t)bt * 8];
  if (ncand == 0) return;
  const double scl = 0.04419417382415922;
  double bestv = -1e300;
  unsigned bestn = 0;
  for (unsigned ci = 0; ci < ncand; ++ci) {
    double s = cacc[(size_t)bt * 8 + ci];
    if (s > bestv) { bestv = s; bestn = clist[(size_t)bt * 8 + 1 + ci]; }
  }
  amaxIdx[bt] = ((unsigned long long)fkey((float)(bestv * scl)) << 32) | bestn;
}

__global__ __launch_bounds__(256) void node_max_kernel(
    const unsigned long long* __restrict__ amaxIdx, unsigned* __restrict__ Mpack) {
  int i = blockIdx.x * 256 + threadIdx.x;
  unsigned long long pk = amaxIdx[i];
  int b = i >> 11;
  unsigned w = (unsigned)pk;
  atomicMax(&Mpack[b * NNODE + w], (unsigned)(pk >> 32));
}

__global__ __launch_bounds__(256) void node_denom_kernel(
    const unsigned long long* __restrict__ amaxIdx, const unsigned* __restrict__ Mpack,
    float* __restrict__ D, float* __restrict__ att_val) {
  int i = blockIdx.x * 256 + threadIdx.x;
  unsigned long long pk = amaxIdx[i];
  int b = i >> 11;
  unsigned w = (unsigned)pk;
  float amaxf = fdec((unsigned)(pk >> 32));
  float Mf = fdec(Mpack[b * NNODE + w]);
  float e = expf(amaxf - Mf);
  att_val[i] = e;
  atomicAdd(&D[b * NNODE + w], e);
}

__global__ __launch_bounds__(256) void att_write_kernel(
    const unsigned long long* __restrict__ amaxIdx, const float* __restrict__ D,
    float* __restrict__ att_val, float* __restrict__ att_out) {
  int i = blockIdx.x * 256 + threadIdx.x;
  unsigned long long pk = amaxIdx[i];
  int b = i >> 11;
  int t = i & (TT - 1);
  unsigned w = (unsigned)pk;
  float a = att_val[i] / D[b * NNODE + w];
  att_val[i] = a;
  att_out[((size_t)b * NNODE + w) * TT + t] = a;
}

__global__ __launch_bounds__(256) void pv_scatter_kernel(
    const unsigned long long* __restrict__ amaxIdx, const float* __restrict__ att_val,
    const unsigned short* __restrict__ v, float* __restrict__ out0) {
  int bt = blockIdx.x;  // [0, B*T)
  int b = bt >> 11;
  float a = att_val[bt];
  unsigned w = (unsigned)amaxIdx[bt];
  const unsigned short* vr = v + (size_t)bt * CC;
  float* orow = out0 + ((size_t)b * NNODE + w) * CC;
  for (int c = threadIdx.x; c < CC; c += 256)
    atomicAdd(&orow[c], a * bf16_tof(vr[c]));
}

extern "C" void kernel_launch(void* const* d_in, const int* in_sizes, int n_in,
                              void* d_out, int out_size, void* d_ws, size_t ws_size,
                              hipStream_t stream) {
  const float* x = (const float*)d_in[0];     // [B,T,C]  f32
  const float* Wq = (const float*)d_in[1];    // [N,T]
  const float* bq = (const float*)d_in[2];    // [N]
  const float* Wk = (const float*)d_in[3];    // [C,C]
  const float* Wv = (const float*)d_in[4];    // [C,C]
  const float* Wout = (const float*)d_in[5];  // [C,C]
  const float* bout = (const float*)d_in[6];  // [C]

  float* out = (float*)d_out;                      // [B,N,C] f32
  float* att_out = out + (size_t)BB * NNODE * CC;  // [B,N,T] f32

  // Workspace layout (f32 word units), ~73 MB total.
  float* ws = (float*)d_ws;
  float* q = ws;                                // B*N*C f32 (reused as out0)
  float* kbuf = q + (size_t)BB * NNODE * CC;    // B*T*C f32
  unsigned short* vbuf = (unsigned short*)(kbuf + (size_t)BB * TT * CC);  // bf16 bits
  unsigned long long* cand1 =
      (unsigned long long*)((unsigned*)vbuf + (size_t)BB * TT * CC / 2);  // B*T*8 u64
  unsigned long long* cand2 = cand1 + (size_t)BB * TT * 8;
  unsigned long long* cand3 = cand2 + (size_t)BB * TT * 8;
  unsigned long long* amaxIdx = cand3 + (size_t)BB * TT * 8;              // B*T u64
  unsigned* Mpack = (unsigned*)(amaxIdx + (size_t)BB * TT);               // B*N u32
  float* D = (float*)(Mpack + (size_t)BB * NNODE);                        // B*N f32
  unsigned* counts = (unsigned*)(D + (size_t)BB * NNODE);                 // 16 u32 (gcount)
  float* att_val = (float*)(counts + 16);                                 // B*T f32
  unsigned* gflag = (unsigned*)(att_val + (size_t)BB * TT);               // B*T u32
  unsigned* clist = gflag + (size_t)BB * TT;                              // B*T*8 u32
  double* cacc = (double*)(clist + (size_t)BB * TT * 8);                  // B*T*8 f64
  float* WkT = (float*)(cacc + (size_t)BB * TT * 8);                      // C*C f32
  float* out0 = q;

  dim3 blk(256);

  // Z1: zero Mpack | D | counts (contiguous)
  fill_zero<<<dim3(64), blk, 0, stream>>>(Mpack, (long long)BB * NNODE * 2 + 16);
  // Z1b: zero clist + cacc (contiguous)
  fill_zero<<<dim3(384), blk, 0, stream>>>(
      clist, (long long)BB * TT * 8 + (long long)BB * TT * 16);
  // Z2: zero att region of d_out
  fill_zero<<<dim3(4096), blk, 0, stream>>>((unsigned*)att_out,
                                            (long long)BB * NNODE * TT);

  // WkT[c][d] = Wk[d][c]  (for coalesced recheck k64)
  transpose_kernel<<<dim3(CC / 32, CC / 32), blk, 0, stream>>>(Wk, WkT, CC, CC);

  // q[b,n,c] = sum_t Wq[n,t] x[b,t,c] + bq[n]  (bf16-split MFMA)
  mfma_gemm<true, false, 1><<<dim3(CC / 128, NNODE / 128, BB), blk, 0, stream>>>(
      Wq, x, q, bq, TT, TT, CC, CC, 0LL, (long long)TT * CC,
      (long long)NNODE * CC, 1.0f);

  // fused k (split, f32) + v (plain, bf16)
  mfma_kv<<<dim3(CC / 128, TT / 128, BB), blk, 0, stream>>>(x, Wk, Wv, kbuf, vbuf);

  // sim (split MFMA) + per-block top-3 candidates
  mfma_sim_top3<<<dim3(TT / 128, NNODE / 128, BB), blk, 0, stream>>>(
      q, kbuf, cand1, cand2, cand3);

  // merge -> amaxIdx + flat flag list + candidate lists
  merge_flag_kernel<<<dim3(BB * TT / 256), blk, 0, stream>>>(
      cand1, cand2, cand3, amaxIdx, counts, gflag, clist);

  // exact f64 recheck: coalesced chunk-parallel partials + finalize
  recheck_partial<<<dim3(NSLOT * NCHUNK), blk, 0, stream>>>(
      x, Wq, bq, WkT, counts, gflag, clist, cacc);
  recheck_final<<<dim3(BB * TT / 256), blk, 0, stream>>>(clist, cacc, amaxIdx);

  // zero out0 (aliases q; q dead after sim)
  fill_zero<<<dim3(2048), blk, 0, stream>>>((unsigned*)out0, (long long)BB * NNODE * CC);

  node_max_kernel<<<dim3(BB * TT / 256), blk, 0, stream>>>(amaxIdx, Mpack);
  node_denom_kernel<<<dim3(BB * TT / 256), blk, 0, stream>>>(amaxIdx, Mpack, D, att_val);
  att_write_kernel<<<dim3(BB * TT / 256), blk, 0, stream>>>(amaxIdx, D, att_val, att_out);

  // sparse PV scatter: out0[b,w,c] += att * v[b,t,c]
  pv_scatter_kernel<<<dim3(BB * TT), blk, 0, stream>>>(amaxIdx, att_val, vbuf, out0);

  // out[b,n,d] = sum_c out0[b,n,c] Wout[d,c] + bout[d]  (plain MFMA, flattened M)
  mfma_gemm<false, true, 2><<<dim3(CC / 128, BB * NNODE / 128, 1), blk, 0, stream>>>(
      out0, Wout, out, bout, CC, CC, CC, CC, 0LL, 0LL, 0LL, 1.0f);
}

// Round 13
// 515.802 us; speedup vs baseline: 1.5809x; 1.5809x over previous
//
#include <hip/hip_runtime.h>
#include <hip/hip_bf16.h>
#include <cfloat>

// Problem constants
#define BB 8
#define TT 2048
#define CC 512
#define NNODE 1024

#define GAP_MARGIN 2e-4f  // screening margin (~40 sigma of bf16-split screen noise)
#define MAXC 6            // max rival candidates per flagged token (fits 8-slot clist)
#define NSLOT 512         // recheck flag capacity (slots)

typedef float f32x4 __attribute__((ext_vector_type(4)));
typedef short bf16x8 __attribute__((ext_vector_type(8)));
typedef float float4v __attribute__((ext_vector_type(4)));

// ---------------------------------------------------------------------------
// Order-preserving f32 <-> u32 key
// ---------------------------------------------------------------------------
__device__ __forceinline__ unsigned fkey(float v) {
  unsigned u = __float_as_uint(v);
  return (u & 0x80000000u) ? ~u : (u | 0x80000000u);
}
__device__ __forceinline__ float fdec(unsigned k) {
  unsigned u = (k & 0x80000000u) ? (k & 0x7FFFFFFFu) : ~k;
  return __uint_as_float(u);
}

// bf16 round-to-nearest-even helpers (bit-level)
__device__ __forceinline__ unsigned short bf16_rn(float f) {
  unsigned u = __float_as_uint(f);
  u += 0x7FFFu + ((u >> 16) & 1u);
  return (unsigned short)(u >> 16);
}
__device__ __forceinline__ float bf16_tof(unsigned short h) {
  return __uint_as_float(((unsigned)h) << 16);
}

// ---------------------------------------------------------------------------
// MFMA GEMM: C[m,n] = alpha*sum_k A[m,k]*B(k,n) (+bias), f32 in/out.
//   SPLIT: bf16-split (hh+hl+lh); TRANS_B: B is [N][K] row-major.
// 128x128 tile, BK=32, 256 threads (4 waves, 2x2), 16x16x32 frags.
// ---------------------------------------------------------------------------
template <bool SPLIT, bool TRANS_B, int BIAS_MODE>
__global__ __launch_bounds__(256) void mfma_gemm(
    const float* __restrict__ A, const float* __restrict__ Bm,
    float* __restrict__ Cp, const float* __restrict__ bias,
    int K, int lda, int ldb, int ldc,
    long long sA, long long sB, long long sC, float alpha) {
  __shared__ unsigned short Ah[128][40], Al[128][40], Bh[128][40], Bl[128][40];

  const int b = blockIdx.z;
  A += (long long)b * sA;
  Bm += (long long)b * sB;
  const int m0 = blockIdx.y * 128;
  const int n0 = blockIdx.x * 128;
  const int tid = threadIdx.x;
  const int l = tid & 63;
  const int wid = tid >> 6;
  const int wy = wid >> 1, wx = wid & 1;
  const int lrow = l & 15, lkb = (l >> 4) * 8;

  f32x4 acc[4][4] = {};

  for (int k0 = 0; k0 < K; k0 += 32) {
    {
      int r = tid >> 3, c = (tid & 7) * 4;
#pragma unroll
      for (int p = 0; p < 4; ++p, r += 32) {
        float4v v = *(const float4v*)(A + (long long)(m0 + r) * lda + k0 + c);
#pragma unroll
        for (int i = 0; i < 4; ++i) {
          unsigned short h = bf16_rn(v[i]);
          Ah[r][c + i] = h;
          if (SPLIT) Al[r][c + i] = bf16_rn(v[i] - bf16_tof(h));
        }
      }
    }
    if (TRANS_B) {
      int r = tid >> 3, c = (tid & 7) * 4;
#pragma unroll
      for (int p = 0; p < 4; ++p, r += 32) {
        float4v v = *(const float4v*)(Bm + (long long)(n0 + r) * ldb + k0 + c);
#pragma unroll
        for (int i = 0; i < 4; ++i) {
          unsigned short h = bf16_rn(v[i]);
          Bh[r][c + i] = h;
          if (SPLIT) Bl[r][c + i] = bf16_rn(v[i] - bf16_tof(h));
        }
      }
    } else {
      int kk = tid >> 5, c = (tid & 31) * 4;
#pragma unroll
      for (int p = 0; p < 4; ++p, kk += 8) {
        float4v v = *(const float4v*)(Bm + (long long)(k0 + kk) * ldb + n0 + c);
#pragma unroll
        for (int i = 0; i < 4; ++i) {
          unsigned short h = bf16_rn(v[i]);
          Bh[c + i][kk] = h;
          if (SPLIT) Bl[c + i][kk] = bf16_rn(v[i] - bf16_tof(h));
        }
      }
    }
    __syncthreads();

    bf16x8 ah[4], bh[4], al[4], bl[4];
#pragma unroll
    for (int mf = 0; mf < 4; ++mf) {
      ah[mf] = *(const bf16x8*)&Ah[wy * 64 + mf * 16 + lrow][lkb];
      if (SPLIT) al[mf] = *(const bf16x8*)&Al[wy * 64 + mf * 16 + lrow][lkb];
    }
#pragma unroll
    for (int nf = 0; nf < 4; ++nf) {
      bh[nf] = *(const bf16x8*)&Bh[wx * 64 + nf * 16 + lrow][lkb];
      if (SPLIT) bl[nf] = *(const bf16x8*)&Bl[wx * 64 + nf * 16 + lrow][lkb];
    }
#pragma unroll
    for (int mf = 0; mf < 4; ++mf)
#pragma unroll
      for (int nf = 0; nf < 4; ++nf) {
        acc[mf][nf] =
            __builtin_amdgcn_mfma_f32_16x16x32_bf16(ah[mf], bh[nf], acc[mf][nf], 0, 0, 0);
        if (SPLIT) {
          acc[mf][nf] =
              __builtin_amdgcn_mfma_f32_16x16x32_bf16(ah[mf], bl[nf], acc[mf][nf], 0, 0, 0);
          acc[mf][nf] =
              __builtin_amdgcn_mfma_f32_16x16x32_bf16(al[mf], bh[nf], acc[mf][nf], 0, 0, 0);
        }
      }
    __syncthreads();
  }

#pragma unroll
  for (int mf = 0; mf < 4; ++mf)
#pragma unroll
    for (int r = 0; r < 4; ++r) {
      int m = m0 + wy * 64 + mf * 16 + (l >> 4) * 4 + r;
#pragma unroll
      for (int nf = 0; nf < 4; ++nf) {
        int n = n0 + wx * 64 + nf * 16 + lrow;
        float v = acc[mf][nf][r] * alpha;
        if (BIAS_MODE == 1) v += bias[m];
        if (BIAS_MODE == 2) v += bias[n];
        Cp[sC * b + (long long)m * ldc + n] = v;
      }
    }
}

// ---------------------------------------------------------------------------
// Fused k (bf16-split, f32 out) + v (plain bf16, bf16 out) projection.
// ---------------------------------------------------------------------------
__global__ __launch_bounds__(256) void mfma_kv(
    const float* __restrict__ x, const float* __restrict__ Wk,
    const float* __restrict__ Wv, float* __restrict__ kout,
    unsigned short* __restrict__ vout) {
  __shared__ unsigned short Ah[128][40], Al[128][40], Bkh[128][40], Bkl[128][40],
      Bvh[128][40];

  const int b = blockIdx.z;
  const float* A = x + (size_t)b * TT * CC;
  const int m0 = blockIdx.y * 128;  // tokens
  const int n0 = blockIdx.x * 128;  // out dim
  const int tid = threadIdx.x;
  const int l = tid & 63;
  const int wid = tid >> 6;
  const int wy = wid >> 1, wx = wid & 1;
  const int lrow = l & 15, lkb = (l >> 4) * 8;

  f32x4 acck[4][4] = {}, accv[4][4] = {};

  for (int k0 = 0; k0 < CC; k0 += 32) {
    {
      int r = tid >> 3, c = (tid & 7) * 4;
#pragma unroll
      for (int p = 0; p < 4; ++p, r += 32) {
        float4v v = *(const float4v*)(A + (size_t)(m0 + r) * CC + k0 + c);
        float4v wk = *(const float4v*)(Wk + (size_t)(n0 + r) * CC + k0 + c);
        float4v wv = *(const float4v*)(Wv + (size_t)(n0 + r) * CC + k0 + c);
#pragma unroll
        for (int i = 0; i < 4; ++i) {
          unsigned short h = bf16_rn(v[i]);
          Ah[r][c + i] = h;
          Al[r][c + i] = bf16_rn(v[i] - bf16_tof(h));
          unsigned short hk = bf16_rn(wk[i]);
          Bkh[r][c + i] = hk;
          Bkl[r][c + i] = bf16_rn(wk[i] - bf16_tof(hk));
          Bvh[r][c + i] = bf16_rn(wv[i]);
        }
      }
    }
    __syncthreads();

    bf16x8 ah[4], al[4], bkh[4], bkl[4], bvh[4];
#pragma unroll
    for (int mf = 0; mf < 4; ++mf) {
      ah[mf] = *(const bf16x8*)&Ah[wy * 64 + mf * 16 + lrow][lkb];
      al[mf] = *(const bf16x8*)&Al[wy * 64 + mf * 16 + lrow][lkb];
    }
#pragma unroll
    for (int nf = 0; nf < 4; ++nf) {
      bkh[nf] = *(const bf16x8*)&Bkh[wx * 64 + nf * 16 + lrow][lkb];
      bkl[nf] = *(const bf16x8*)&Bkl[wx * 64 + nf * 16 + lrow][lkb];
      bvh[nf] = *(const bf16x8*)&Bvh[wx * 64 + nf * 16 + lrow][lkb];
    }
#pragma unroll
    for (int mf = 0; mf < 4; ++mf)
#pragma unroll
      for (int nf = 0; nf < 4; ++nf) {
        acck[mf][nf] =
            __builtin_amdgcn_mfma_f32_16x16x32_bf16(ah[mf], bkh[nf], acck[mf][nf], 0, 0, 0);
        acck[mf][nf] =
            __builtin_amdgcn_mfma_f32_16x16x32_bf16(ah[mf], bkl[nf], acck[mf][nf], 0, 0, 0);
        acck[mf][nf] =
            __builtin_amdgcn_mfma_f32_16x16x32_bf16(al[mf], bkh[nf], acck[mf][nf], 0, 0, 0);
        accv[mf][nf] =
            __builtin_amdgcn_mfma_f32_16x16x32_bf16(ah[mf], bvh[nf], accv[mf][nf], 0, 0, 0);
      }
    __syncthreads();
  }

#pragma unroll
  for (int mf = 0; mf < 4; ++mf)
#pragma unroll
    for (int r = 0; r < 4; ++r) {
      int m = m0 + wy * 64 + mf * 16 + (l >> 4) * 4 + r;
#pragma unroll
      for (int nf = 0; nf < 4; ++nf) {
        int n = n0 + wx * 64 + nf * 16 + lrow;
        size_t off = ((size_t)b * TT + m) * CC + n;
        kout[off] = acck[mf][nf][r];
        vout[off] = bf16_rn(accv[mf][nf][r]);
      }
    }
}

// ---------------------------------------------------------------------------
// sim (bf16-split MFMA, no store) + per-block per-token top-3 candidates.
// ---------------------------------------------------------------------------
__global__ __launch_bounds__(256) void mfma_sim_top3(
    const float* __restrict__ q, const float* __restrict__ kb,
    unsigned long long* __restrict__ cand1, unsigned long long* __restrict__ cand2,
    unsigned long long* __restrict__ cand3) {
  __shared__ unsigned short Ah[128][40], Al[128][40], Bh[128][40], Bl[128][40];
  __shared__ unsigned long long c1[128], c2[128], c3[128];

  const int b = blockIdx.z;
  const float* A = q + (size_t)b * NNODE * CC;
  const float* Bm = kb + (size_t)b * TT * CC;
  const int n0 = blockIdx.y * 128;  // nodes
  const int t0 = blockIdx.x * 128;  // tokens
  const int tid = threadIdx.x;
  const int l = tid & 63;
  const int wid = tid >> 6;
  const int wy = wid >> 1, wx = wid & 1;
  const int lrow = l & 15, lkb = (l >> 4) * 8;

  if (tid < 128) { c1[tid] = 0ULL; c2[tid] = 0ULL; c3[tid] = 0ULL; }

  f32x4 acc[4][4] = {};

  for (int k0 = 0; k0 < CC; k0 += 32) {
    {
      int r = tid >> 3, c = (tid & 7) * 4;
#pragma unroll
      for (int p = 0; p < 4; ++p, r += 32) {
        float4v v = *(const float4v*)(A + (size_t)(n0 + r) * CC + k0 + c);
        float4v w = *(const float4v*)(Bm + (size_t)(t0 + r) * CC + k0 + c);
#pragma unroll
        for (int i = 0; i < 4; ++i) {
          unsigned short h = bf16_rn(v[i]);
          Ah[r][c + i] = h;
          Al[r][c + i] = bf16_rn(v[i] - bf16_tof(h));
          unsigned short hb = bf16_rn(w[i]);
          Bh[r][c + i] = hb;
          Bl[r][c + i] = bf16_rn(w[i] - bf16_tof(hb));
        }
      }
    }
    __syncthreads();

    bf16x8 ah[4], al[4], bh[4], bl[4];
#pragma unroll
    for (int mf = 0; mf < 4; ++mf) {
      ah[mf] = *(const bf16x8*)&Ah[wy * 64 + mf * 16 + lrow][lkb];
      al[mf] = *(const bf16x8*)&Al[wy * 64 + mf * 16 + lrow][lkb];
    }
#pragma unroll
    for (int nf = 0; nf < 4; ++nf) {
      bh[nf] = *(const bf16x8*)&Bh[wx * 64 + nf * 16 + lrow][lkb];
      bl[nf] = *(const bf16x8*)&Bl[wx * 64 + nf * 16 + lrow][lkb];
    }
#pragma unroll
    for (int mf = 0; mf < 4; ++mf)
#pragma unroll
      for (int nf = 0; nf < 4; ++nf) {
        acc[mf][nf] =
            __builtin_amdgcn_mfma_f32_16x16x32_bf16(ah[mf], bh[nf], acc[mf][nf], 0, 0, 0);
        acc[mf][nf] =
            __builtin_amdgcn_mfma_f32_16x16x32_bf16(ah[mf], bl[nf], acc[mf][nf], 0, 0, 0);
        acc[mf][nf] =
            __builtin_amdgcn_mfma_f32_16x16x32_bf16(al[mf], bh[nf], acc[mf][nf], 0, 0, 0);
      }
    __syncthreads();
  }

  const float scl = 0.04419417382415922f;
#pragma unroll
  for (int nf = 0; nf < 4; ++nf) {
    int tcol = wx * 64 + nf * 16 + lrow;
    unsigned long long m = 0ULL;
#pragma unroll
    for (int mf = 0; mf < 4; ++mf)
#pragma unroll
      for (int r = 0; r < 4; ++r) {
        unsigned node = (unsigned)(n0 + wy * 64 + mf * 16 + (l >> 4) * 4 + r);
        unsigned long long pk =
            ((unsigned long long)fkey(acc[mf][nf][r] * scl) << 32) | node;
        if (pk > m) m = pk;
      }
    atomicMax(&c1[tcol], m);
  }
  __syncthreads();
#pragma unroll
  for (int nf = 0; nf < 4; ++nf) {
    int tcol = wx * 64 + nf * 16 + lrow;
    unsigned w1 = (unsigned)c1[tcol];
    unsigned long long m = 0ULL;
#pragma unroll
    for (int mf = 0; mf < 4; ++mf)
#pragma unroll
      for (int r = 0; r < 4; ++r) {
        unsigned node = (unsigned)(n0 + wy * 64 + mf * 16 + (l >> 4) * 4 + r);
        if (node == w1) continue;
        unsigned long long pk =
            ((unsigned long long)fkey(acc[mf][nf][r] * scl) << 32) | node;
        if (pk > m) m = pk;
      }
    if (m) atomicMax(&c2[tcol], m);
  }
  __syncthreads();
#pragma unroll
  for (int nf = 0; nf < 4; ++nf) {
    int tcol = wx * 64 + nf * 16 + lrow;
    unsigned w1 = (unsigned)c1[tcol];
    unsigned w2 = (unsigned)c2[tcol];
    unsigned long long m = 0ULL;
#pragma unroll
    for (int mf = 0; mf < 4; ++mf)
#pragma unroll
      for (int r = 0; r < 4; ++r) {
        unsigned node = (unsigned)(n0 + wy * 64 + mf * 16 + (l >> 4) * 4 + r);
        if (node == w1 || node == w2) continue;
        unsigned long long pk =
            ((unsigned long long)fkey(acc[mf][nf][r] * scl) << 32) | node;
        if (pk > m) m = pk;
      }
    if (m) atomicMax(&c3[tcol], m);
  }
  __syncthreads();
  if (tid < 128) {
    size_t base = ((size_t)b * TT + (t0 + tid)) * 8 + blockIdx.y;
    cand1[base] = c1[tid];
    cand2[base] = c2[tid];
    cand3[base] = c3[tid];
  }
}

__global__ __launch_bounds__(256) void fill_zero(unsigned* __restrict__ p, long long n) {
  long long i = (long long)blockIdx.x * 256 + threadIdx.x;
  long long stride = (long long)gridDim.x * 256;
  for (; i < n; i += stride) p[i] = 0u;
}

// 32x32 tile transpose: dst[c][r] = src[r][c].
__global__ __launch_bounds__(256) void transpose_kernel(
    const float* __restrict__ src, float* __restrict__ dst, int R, int C) {
  __shared__ float tile[32][33];
  int r0 = blockIdx.y * 32, c0 = blockIdx.x * 32;
  int tx = threadIdx.x & 31, ty = threadIdx.x >> 5;  // 32 x 8
#pragma unroll
  for (int i = 0; i < 4; ++i)
    tile[ty + i * 8][tx] = src[(size_t)(r0 + ty + i * 8) * C + c0 + tx];
  __syncthreads();
#pragma unroll
  for (int i = 0; i < 4; ++i)
    dst[(size_t)(c0 + ty + i * 8) * R + r0 + tx] = tile[tx][ty + i * 8];
}

// ---------------------------------------------------------------------------
// Merge 8x(top-3) -> global top1 + rivals within GAP_MARGIN -> FLAT flag list.
// ---------------------------------------------------------------------------
__global__ __launch_bounds__(256) void merge_flag_kernel(
    const unsigned long long* __restrict__ cand1,
    const unsigned long long* __restrict__ cand2,
    const unsigned long long* __restrict__ cand3,
    unsigned long long* __restrict__ amaxIdx,
    unsigned* __restrict__ gcount, unsigned* __restrict__ gflag,
    unsigned* __restrict__ clist) {
  int bt = blockIdx.x * 256 + threadIdx.x;  // [0, B*T)
  unsigned long long best = 0ULL;
#pragma unroll
  for (int nb = 0; nb < 8; ++nb) {
    unsigned long long v = cand1[(size_t)bt * 8 + nb];
    if (v > best) best = v;
  }
  amaxIdx[bt] = best;
  float v1 = fdec((unsigned)(best >> 32));
  float thr = v1 - GAP_MARGIN;
  unsigned bestnode = (unsigned)best;

  unsigned nodes[MAXC];
  int cnt = 0;
#pragma unroll
  for (int nb = 0; nb < 8; ++nb) {
    unsigned long long cs[3] = {cand1[(size_t)bt * 8 + nb], cand2[(size_t)bt * 8 + nb],
                                cand3[(size_t)bt * 8 + nb]};
#pragma unroll
    for (int s = 0; s < 3; ++s) {
      float v = fdec((unsigned)(cs[s] >> 32));
      unsigned nd = (unsigned)cs[s];
      if (v >= thr && nd != bestnode && cnt < MAXC) nodes[cnt++] = nd;
    }
  }
  if (cnt > 0) {
    unsigned p = atomicAdd(gcount, 1u);
    if (p < NSLOT) {
      gflag[p] = (unsigned)bt;
      clist[(size_t)bt * 8] = (unsigned)(cnt + 1);
      clist[(size_t)bt * 8 + 1] = bestnode;
      for (int i = 0; i < cnt; ++i) clist[(size_t)bt * 8 + 2 + i] = nodes[i];
    }
  }
}

// ---------------------------------------------------------------------------
// Recheck phase A: k64[fi][d] = sum_c x_t[c] * Wk[d][c]  (f64, exact).
// Grid NSLOT x 8 d-chunks. Block: 64 d's x 4 c-parts (coalesced via WkT).
// ---------------------------------------------------------------------------
__global__ __launch_bounds__(256) void recheck_k64(
    const float* __restrict__ x, const float* __restrict__ WkT,
    const unsigned* __restrict__ gcount, const unsigned* __restrict__ gflag,
    double* __restrict__ k64g) {
  __shared__ float xs[CC];
  __shared__ double kpart[64][4];

  const unsigned cnt = min(*gcount, (unsigned)NSLOT);
  const int slot = blockIdx.x >> 3;
  const int dchunk = blockIdx.x & 7;
  if ((unsigned)slot >= cnt) return;
  const int tid = threadIdx.x;

  unsigned bt = gflag[slot];
  int b = bt >> 11, t = bt & (TT - 1);
  const float* xr = x + ((size_t)b * TT + t) * CC;
  xs[tid] = xr[tid];
  xs[tid + 256] = xr[tid + 256];
  __syncthreads();

  const int d = dchunk * 64 + (tid & 63);
  const int part = tid >> 6;  // 4 parts x 128 c
  const int cbase = part * 128;
  double a0 = 0.0, a1 = 0.0;
#pragma unroll 8
  for (int i = 0; i < 64; ++i) {
    int c = cbase + 2 * i;
    a0 = fma((double)WkT[(size_t)c * CC + d], (double)xs[c], a0);
    a1 = fma((double)WkT[(size_t)(c + 1) * CC + d], (double)xs[c + 1], a1);
  }
  kpart[tid & 63][part] = a0 + a1;
  __syncthreads();
  if (tid < 64) {
    double s = (kpart[tid][0] + kpart[tid][1]) + (kpart[tid][2] + kpart[tid][3]);
    k64g[(size_t)slot * CC + dchunk * 64 + tid] = s;
  }
}

// ---------------------------------------------------------------------------
// Recheck phase B: z[fi][t'] = sum_c x[t'][c] * k64[fi][c]  (f64 acc, f32 out).
// Grid NSLOT x 32 token-chunks (64 tokens each). LDS-staged x tiles.
// ---------------------------------------------------------------------------
__global__ __launch_bounds__(256) void recheck_z(
    const float* __restrict__ x, const unsigned* __restrict__ gcount,
    const unsigned* __restrict__ gflag, const double* __restrict__ k64g,
    float* __restrict__ zg) {
  __shared__ float tile[64][129];  // 33 KB
  __shared__ double k64l[CC];      // 4 KB
  __shared__ double zp[64][4];     // 2 KB

  const unsigned cnt = min(*gcount, (unsigned)NSLOT);
  const int slot = blockIdx.x >> 5;
  const int tchunk = blockIdx.x & 31;
  if ((unsigned)slot >= cnt) return;
  const int tid = threadIdx.x;

  unsigned bt = gflag[slot];
  int b = bt >> 11;
  const float* xb = x + (size_t)b * TT * CC;
  const int tok0 = tchunk * 64;

  k64l[tid] = k64g[(size_t)slot * CC + tid];
  k64l[tid + 256] = k64g[(size_t)slot * CC + tid + 256];

  const int tok = tid >> 2;      // 64 tokens
  const int part = tid & 3;      // 4 c-parts of 32 per pass
  double z0 = 0.0, z1 = 0.0;

  for (int p = 0; p < 4; ++p) {
    __syncthreads();
    int c0 = p * 128;
#pragma unroll
    for (int j = 0; j < 32; ++j) {
      int lin = j * 256 + tid;
      int r = lin >> 7, col = lin & 127;
      tile[r][col] = xb[(size_t)(tok0 + r) * CC + c0 + col];
    }
    __syncthreads();
#pragma unroll
    for (int i = 0; i < 16; ++i) {
      int cl = part * 32 + 2 * i;
      z0 = fma((double)tile[tok][cl], k64l[c0 + cl], z0);
      z1 = fma((double)tile[tok][cl + 1], k64l[c0 + cl + 1], z1);
    }
  }
  zp[tok][part] = z0 + z1;
  __syncthreads();
  if (tid < 64) {
    double z = (zp[tid][0] + zp[tid][1]) + (zp[tid][2] + zp[tid][3]);
    zg[(size_t)slot * TT + tok0 + tid] = (float)z;
  }
}

// ---------------------------------------------------------------------------
// Recheck phase C: sim64(n) = Wq[n,:].z + bq[n]*sum(k64); argmax candidates.
// Grid NSLOT. Deterministic fixed-order reduction.
// ---------------------------------------------------------------------------
__global__ __launch_bounds__(256) void recheck_cand(
    const float* __restrict__ Wq, const float* __restrict__ bq,
    const unsigned* __restrict__ gcount, const unsigned* __restrict__ gflag,
    const unsigned* __restrict__ clist, const double* __restrict__ k64g,
    const float* __restrict__ zg, unsigned long long* __restrict__ amaxIdx) {
  __shared__ double red[4];
  __shared__ double ssumS;

  const unsigned cnt = min(*gcount, (unsigned)NSLOT);
  const int slot = blockIdx.x;
  if ((unsigned)slot >= cnt) return;
  const int tid = threadIdx.x;

  unsigned bt = gflag[slot];

  // ssum = sum(k64)
  double ps = k64g[(size_t)slot * CC + tid] + k64g[(size_t)slot * CC + tid + 256];
#pragma unroll
  for (int off = 32; off > 0; off >>= 1) ps += __shfl_down(ps, off, 64);
  if ((tid & 63) == 0) red[tid >> 6] = ps;
  __syncthreads();
  if (tid == 0) ssumS = (red[0] + red[1]) + (red[2] + red[3]);
  __syncthreads();
  const double ssum = ssumS;

  const double scl = 0.04419417382415922;
  unsigned ncand = clist[(size_t)bt * 8];
  unsigned long long bestpk = 0ULL;
  double bestv = -1e300;
  for (unsigned ci = 0; ci < ncand; ++ci) {
    unsigned n = clist[(size_t)bt * 8 + 1 + ci];
    const float* wq = Wq + (size_t)n * TT;
    const float* zr = zg + (size_t)slot * TT;
    double a = 0.0;
#pragma unroll
    for (int i = 0; i < TT / 256; ++i) {
      int tp = tid + i * 256;
      a = fma((double)wq[tp], (double)zr[tp], a);
    }
#pragma unroll
    for (int off = 32; off > 0; off >>= 1) a += __shfl_down(a, off, 64);
    if ((tid & 63) == 0) red[tid >> 6] = a;
    __syncthreads();
    double s = ((red[0] + red[1]) + (red[2] + red[3])) + (double)bq[n] * ssum;
    if (s > bestv) {
      bestv = s;
      bestpk = ((unsigned long long)fkey((float)(s * scl)) << 32) | n;
    }
    __syncthreads();
  }
  if (tid == 0) amaxIdx[bt] = bestpk;
}

__global__ __launch_bounds__(256) void node_max_kernel(
    const unsigned long long* __restrict__ amaxIdx, unsigned* __restrict__ Mpack) {
  int i = blockIdx.x * 256 + threadIdx.x;
  unsigned long long pk = amaxIdx[i];
  int b = i >> 11;
  unsigned w = (unsigned)pk;
  atomicMax(&Mpack[b * NNODE + w], (unsigned)(pk >> 32));
}

__global__ __launch_bounds__(256) void node_denom_kernel(
    const unsigned long long* __restrict__ amaxIdx, const unsigned* __restrict__ Mpack,
    float* __restrict__ D, float* __restrict__ att_val) {
  int i = blockIdx.x * 256 + threadIdx.x;
  unsigned long long pk = amaxIdx[i];
  int b = i >> 11;
  unsigned w = (unsigned)pk;
  float amaxf = fdec((unsigned)(pk >> 32));
  float Mf = fdec(Mpack[b * NNODE + w]);
  float e = expf(amaxf - Mf);
  att_val[i] = e;
  atomicAdd(&D[b * NNODE + w], e);
}

__global__ __launch_bounds__(256) void att_write_kernel(
    const unsigned long long* __restrict__ amaxIdx, const float* __restrict__ D,
    float* __restrict__ att_val, float* __restrict__ att_out) {
  int i = blockIdx.x * 256 + threadIdx.x;
  unsigned long long pk = amaxIdx[i];
  int b = i >> 11;
  int t = i & (TT - 1);
  unsigned w = (unsigned)pk;
  float a = att_val[i] / D[b * NNODE + w];
  att_val[i] = a;
  att_out[((size_t)b * NNODE + w) * TT + t] = a;
}

__global__ __launch_bounds__(256) void pv_scatter_kernel(
    const unsigned long long* __restrict__ amaxIdx, const float* __restrict__ att_val,
    const unsigned short* __restrict__ v, float* __restrict__ out0) {
  int bt = blockIdx.x;  // [0, B*T)
  int b = bt >> 11;
  float a = att_val[bt];
  unsigned w = (unsigned)amaxIdx[bt];
  const unsigned short* vr = v + (size_t)bt * CC;
  float* orow = out0 + ((size_t)b * NNODE + w) * CC;
  for (int c = threadIdx.x; c < CC; c += 256)
    atomicAdd(&orow[c], a * bf16_tof(vr[c]));
}

extern "C" void kernel_launch(void* const* d_in, const int* in_sizes, int n_in,
                              void* d_out, int out_size, void* d_ws, size_t ws_size,
                              hipStream_t stream) {
  const float* x = (const float*)d_in[0];     // [B,T,C]  f32
  const float* Wq = (const float*)d_in[1];    // [N,T]
  const float* bq = (const float*)d_in[2];    // [N]
  const float* Wk = (const float*)d_in[3];    // [C,C]
  const float* Wv = (const float*)d_in[4];    // [C,C]
  const float* Wout = (const float*)d_in[5];  // [C,C]
  const float* bout = (const float*)d_in[6];  // [C]

  float* out = (float*)d_out;                      // [B,N,C] f32
  float* att_out = out + (size_t)BB * NNODE * CC;  // [B,N,T] f32

  // Workspace layout (f32 word units), ~75 MB total.
  float* ws = (float*)d_ws;
  float* q = ws;                                // B*N*C f32 (reused as out0)
  float* kbuf = q + (size_t)BB * NNODE * CC;    // B*T*C f32
  unsigned short* vbuf = (unsigned short*)(kbuf + (size_t)BB * TT * CC);  // bf16 bits
  unsigned long long* cand1 =
      (unsigned long long*)((unsigned*)vbuf + (size_t)BB * TT * CC / 2);  // B*T*8 u64
  unsigned long long* cand2 = cand1 + (size_t)BB * TT * 8;
  unsigned long long* cand3 = cand2 + (size_t)BB * TT * 8;
  unsigned long long* amaxIdx = cand3 + (size_t)BB * TT * 8;              // B*T u64
  unsigned* Mpack = (unsigned*)(amaxIdx + (size_t)BB * TT);               // B*N u32
  float* D = (float*)(Mpack + (size_t)BB * NNODE);                        // B*N f32
  unsigned* counts = (unsigned*)(D + (size_t)BB * NNODE);                 // 16 u32 (gcount)
  float* att_val = (float*)(counts + 16);                                 // B*T f32
  unsigned* gflag = (unsigned*)(att_val + (size_t)BB * TT);               // B*T u32
  unsigned* clist = gflag + (size_t)BB * TT;                              // B*T*8 u32
  float* WkT = (float*)(clist + (size_t)BB * TT * 8);                     // C*C f32
  double* k64g = (double*)(WkT + (size_t)CC * CC);                        // NSLOT*C f64
  float* zg = (float*)(k64g + (size_t)NSLOT * CC);                        // NSLOT*T f32
  float* out0 = q;

  dim3 blk(256);

  // Z1: zero Mpack | D | counts (contiguous)
  fill_zero<<<dim3(64), blk, 0, stream>>>(Mpack, (long long)BB * NNODE * 2 + 16);
  // Z2: zero att region of d_out
  fill_zero<<<dim3(4096), blk, 0, stream>>>((unsigned*)att_out,
                                            (long long)BB * NNODE * TT);

  // WkT[c][d] = Wk[d][c]  (for coalesced recheck k64)
  transpose_kernel<<<dim3(CC / 32, CC / 32), blk, 0, stream>>>(Wk, WkT, CC, CC);

  // q[b,n,c] = sum_t Wq[n,t] x[b,t,c] + bq[n]  (bf16-split MFMA)
  mfma_gemm<true, false, 1><<<dim3(CC / 128, NNODE / 128, BB), blk, 0, stream>>>(
      Wq, x, q, bq, TT, TT, CC, CC, 0LL, (long long)TT * CC,
      (long long)NNODE * CC, 1.0f);

  // fused k (split, f32) + v (plain, bf16)
  mfma_kv<<<dim3(CC / 128, TT / 128, BB), blk, 0, stream>>>(x, Wk, Wv, kbuf, vbuf);

  // sim (split MFMA) + per-block top-3 candidates
  mfma_sim_top3<<<dim3(TT / 128, NNODE / 128, BB), blk, 0, stream>>>(
      q, kbuf, cand1, cand2, cand3);

  // merge -> amaxIdx + flat flag list + candidate lists
  merge_flag_kernel<<<dim3(BB * TT / 256), blk, 0, stream>>>(
      cand1, cand2, cand3, amaxIdx, counts, gflag, clist);

  // exact f64 recheck: 3 phase-parallel kernels (A: k64, B: z, C: candidates)
  recheck_k64<<<dim3(NSLOT * 8), blk, 0, stream>>>(x, WkT, counts, gflag, k64g);
  recheck_z<<<dim3(NSLOT * 32), blk, 0, stream>>>(x, counts, gflag, k64g, zg);
  recheck_cand<<<dim3(NSLOT), blk, 0, stream>>>(Wq, bq, counts, gflag, clist,
                                                k64g, zg, amaxIdx);

  // zero out0 (aliases q; q dead after sim)
  fill_zero<<<dim3(2048), blk, 0, stream>>>((unsigned*)out0, (long long)BB * NNODE * CC);

  node_max_kernel<<<dim3(BB * TT / 256), blk, 0, stream>>>(amaxIdx, Mpack);
  node_denom_kernel<<<dim3(BB * TT / 256), blk, 0, stream>>>(amaxIdx, Mpack, D, att_val);
  att_write_kernel<<<dim3(BB * TT / 256), blk, 0, stream>>>(amaxIdx, D, att_val, att_out);

  // sparse PV scatter: out0[b,w,c] += att * v[b,t,c]
  pv_scatter_kernel<<<dim3(BB * TT), blk, 0, stream>>>(amaxIdx, att_val, vbuf, out0);

  // out[b,n,d] = sum_c out0[b,n,c] Wout[d,c] + bout[d]  (plain MFMA, flattened M)
  mfma_gemm<false, true, 2><<<dim3(CC / 128, BB * NNODE / 128, 1), blk, 0, stream>>>(
      out0, Wout, out, bout, CC, CC, CC, CC, 0LL, 0LL, 0LL, 1.0f);
}

// Round 14
// 434.080 us; speedup vs baseline: 1.8786x; 1.1883x over previous
//
#include <hip/hip_runtime.h>
#include <hip/hip_bf16.h>
#include <cfloat>

// Problem constants
#define BB 8
#define TT 2048
#define CC 512
#define NNODE 1024

#define GAP_MARGIN 2e-4f  // screening margin (~40 sigma of bf16-split screen noise)
#define MAXC 6            // max rival candidates per flagged token (fits 8-slot clist)
#define NSLOT 512         // recheck flag capacity (slots)

typedef float f32x4 __attribute__((ext_vector_type(4)));
typedef short bf16x8 __attribute__((ext_vector_type(8)));
typedef float float4v __attribute__((ext_vector_type(4)));

// ---------------------------------------------------------------------------
// Order-preserving f32 <-> u32 key
// ---------------------------------------------------------------------------
__device__ __forceinline__ unsigned fkey(float v) {
  unsigned u = __float_as_uint(v);
  return (u & 0x80000000u) ? ~u : (u | 0x80000000u);
}
__device__ __forceinline__ float fdec(unsigned k) {
  unsigned u = (k & 0x80000000u) ? (k & 0x7FFFFFFFu) : ~k;
  return __uint_as_float(u);
}

// bf16 round-to-nearest-even helpers (bit-level)
__device__ __forceinline__ unsigned short bf16_rn(float f) {
  unsigned u = __float_as_uint(f);
  u += 0x7FFFu + ((u >> 16) & 1u);
  return (unsigned short)(u >> 16);
}
__device__ __forceinline__ float bf16_tof(unsigned short h) {
  return __uint_as_float(((unsigned)h) << 16);
}

// ---------------------------------------------------------------------------
// MFMA GEMM (512 threads, 8 waves 2Mx4N): C[m,n] = alpha*sum_k A[m,k]*B(k,n).
//   SPLIT: bf16-split (hh+hl+lh); TRANS_B: B is [N][K] row-major, else [K][N]
//   (transposed during staging via conflict-free row-chunk writes).
// 128x128 tile, BK=32. Row pad 40 u16 = 5x16B slots (5 coprime 8 -> b128
// accesses at [r][8k] spread uniformly over bank groups; conflict-free).
// ---------------------------------------------------------------------------
template <bool SPLIT, bool TRANS_B, int BIAS_MODE>
__global__ __launch_bounds__(512) void mfma_gemm(
    const float* __restrict__ A, const float* __restrict__ Bm,
    float* __restrict__ Cp, const float* __restrict__ bias,
    int K, int lda, int ldb, int ldc,
    long long sA, long long sB, long long sC, float alpha) {
  __shared__ unsigned short Ah[128][40], Al[128][40], Bh[128][40], Bl[128][40];

  const int b = blockIdx.z;
  A += (long long)b * sA;
  Bm += (long long)b * sB;
  const int m0 = blockIdx.y * 128;
  const int n0 = blockIdx.x * 128;
  const int tid = threadIdx.x;
  const int l = tid & 63;
  const int wid = tid >> 6;        // 8 waves
  const int wy = wid >> 2;         // 0..1 -> 64-row band
  const int wx = wid & 3;          // 0..3 -> 32-col band
  const int lrow = l & 15, lkb = (l >> 4) * 8;

  f32x4 acc[4][2] = {};

  for (int k0 = 0; k0 < K; k0 += 32) {
    // A tile: 128x32, contiguous rows; 2 passes x 512 threads x float4.
#pragma unroll
    for (int p = 0; p < 2; ++p) {
      int idx = tid + p * 512;
      int r = idx >> 3, c = (idx & 7) * 4;
      float4v v = *(const float4v*)(A + (long long)(m0 + r) * lda + k0 + c);
#pragma unroll
      for (int i = 0; i < 4; ++i) {
        unsigned short h = bf16_rn(v[i]);
        Ah[r][c + i] = h;
        if (SPLIT) Al[r][c + i] = bf16_rn(v[i] - bf16_tof(h));
      }
    }
    if (TRANS_B) {
      // B [N][K]: same contiguous pattern.
#pragma unroll
      for (int p = 0; p < 2; ++p) {
        int idx = tid + p * 512;
        int r = idx >> 3, c = (idx & 7) * 4;
        float4v v = *(const float4v*)(Bm + (long long)(n0 + r) * ldb + k0 + c);
#pragma unroll
        for (int i = 0; i < 4; ++i) {
          unsigned short h = bf16_rn(v[i]);
          Bh[r][c + i] = h;
          if (SPLIT) Bl[r][c + i] = bf16_rn(v[i] - bf16_tof(h));
        }
      }
    } else {
      // B [K][N] transpose staging, conflict-free:
      // thread owns LDS row n (consecutive lanes -> consecutive n), reads its
      // 8 k-values as scalar loads (coalesced per-k), writes ONE b128 chunk.
      int n = tid & 127;
      int kq = tid >> 7;  // 0..3
      float vals[8];
#pragma unroll
      for (int j = 0; j < 8; ++j)
        vals[j] = Bm[(long long)(k0 + kq * 8 + j) * ldb + n0 + n];
      bf16x8 hv, lv;
#pragma unroll
      for (int j = 0; j < 8; ++j) {
        unsigned short h = bf16_rn(vals[j]);
        hv[j] = (short)h;
        if (SPLIT) lv[j] = (short)bf16_rn(vals[j] - bf16_tof(h));
      }
      *(bf16x8*)&Bh[n][kq * 8] = hv;
      if (SPLIT) *(bf16x8*)&Bl[n][kq * 8] = lv;
    }
    __syncthreads();

    bf16x8 ah[4], al[4], bh[2], bl[2];
#pragma unroll
    for (int mf = 0; mf < 4; ++mf) {
      ah[mf] = *(const bf16x8*)&Ah[wy * 64 + mf * 16 + lrow][lkb];
      if (SPLIT) al[mf] = *(const bf16x8*)&Al[wy * 64 + mf * 16 + lrow][lkb];
    }
#pragma unroll
    for (int nf = 0; nf < 2; ++nf) {
      bh[nf] = *(const bf16x8*)&Bh[wx * 32 + nf * 16 + lrow][lkb];
      if (SPLIT) bl[nf] = *(const bf16x8*)&Bl[wx * 32 + nf * 16 + lrow][lkb];
    }
#pragma unroll
    for (int mf = 0; mf < 4; ++mf)
#pragma unroll
      for (int nf = 0; nf < 2; ++nf) {
        acc[mf][nf] =
            __builtin_amdgcn_mfma_f32_16x16x32_bf16(ah[mf], bh[nf], acc[mf][nf], 0, 0, 0);
        if (SPLIT) {
          acc[mf][nf] =
              __builtin_amdgcn_mfma_f32_16x16x32_bf16(ah[mf], bl[nf], acc[mf][nf], 0, 0, 0);
          acc[mf][nf] =
              __builtin_amdgcn_mfma_f32_16x16x32_bf16(al[mf], bh[nf], acc[mf][nf], 0, 0, 0);
        }
      }
    __syncthreads();
  }

#pragma unroll
  for (int mf = 0; mf < 4; ++mf)
#pragma unroll
    for (int r = 0; r < 4; ++r) {
      int m = m0 + wy * 64 + mf * 16 + (l >> 4) * 4 + r;
#pragma unroll
      for (int nf = 0; nf < 2; ++nf) {
        int n = n0 + wx * 32 + nf * 16 + lrow;
        float v = acc[mf][nf][r] * alpha;
        if (BIAS_MODE == 1) v += bias[m];
        if (BIAS_MODE == 2) v += bias[n];
        Cp[sC * b + (long long)m * ldc + n] = v;
      }
    }
}

// ---------------------------------------------------------------------------
// Fused k (bf16-split, f32 out) + v (plain bf16, bf16 out) projection.
// (256 threads, unchanged: contiguous staging, conflict-free.)
// ---------------------------------------------------------------------------
__global__ __launch_bounds__(256) void mfma_kv(
    const float* __restrict__ x, const float* __restrict__ Wk,
    const float* __restrict__ Wv, float* __restrict__ kout,
    unsigned short* __restrict__ vout) {
  __shared__ unsigned short Ah[128][40], Al[128][40], Bkh[128][40], Bkl[128][40],
      Bvh[128][40];

  const int b = blockIdx.z;
  const float* A = x + (size_t)b * TT * CC;
  const int m0 = blockIdx.y * 128;  // tokens
  const int n0 = blockIdx.x * 128;  // out dim
  const int tid = threadIdx.x;
  const int l = tid & 63;
  const int wid = tid >> 6;
  const int wy = wid >> 1, wx = wid & 1;
  const int lrow = l & 15, lkb = (l >> 4) * 8;

  f32x4 acck[4][4] = {}, accv[4][4] = {};

  for (int k0 = 0; k0 < CC; k0 += 32) {
    {
      int r = tid >> 3, c = (tid & 7) * 4;
#pragma unroll
      for (int p = 0; p < 4; ++p, r += 32) {
        float4v v = *(const float4v*)(A + (size_t)(m0 + r) * CC + k0 + c);
        float4v wk = *(const float4v*)(Wk + (size_t)(n0 + r) * CC + k0 + c);
        float4v wv = *(const float4v*)(Wv + (size_t)(n0 + r) * CC + k0 + c);
#pragma unroll
        for (int i = 0; i < 4; ++i) {
          unsigned short h = bf16_rn(v[i]);
          Ah[r][c + i] = h;
          Al[r][c + i] = bf16_rn(v[i] - bf16_tof(h));
          unsigned short hk = bf16_rn(wk[i]);
          Bkh[r][c + i] = hk;
          Bkl[r][c + i] = bf16_rn(wk[i] - bf16_tof(hk));
          Bvh[r][c + i] = bf16_rn(wv[i]);
        }
      }
    }
    __syncthreads();

    bf16x8 ah[4], al[4], bkh[4], bkl[4], bvh[4];
#pragma unroll
    for (int mf = 0; mf < 4; ++mf) {
      ah[mf] = *(const bf16x8*)&Ah[wy * 64 + mf * 16 + lrow][lkb];
      al[mf] = *(const bf16x8*)&Al[wy * 64 + mf * 16 + lrow][lkb];
    }
#pragma unroll
    for (int nf = 0; nf < 4; ++nf) {
      bkh[nf] = *(const bf16x8*)&Bkh[wx * 64 + nf * 16 + lrow][lkb];
      bkl[nf] = *(const bf16x8*)&Bkl[wx * 64 + nf * 16 + lrow][lkb];
      bvh[nf] = *(const bf16x8*)&Bvh[wx * 64 + nf * 16 + lrow][lkb];
    }
#pragma unroll
    for (int mf = 0; mf < 4; ++mf)
#pragma unroll
      for (int nf = 0; nf < 4; ++nf) {
        acck[mf][nf] =
            __builtin_amdgcn_mfma_f32_16x16x32_bf16(ah[mf], bkh[nf], acck[mf][nf], 0, 0, 0);
        acck[mf][nf] =
            __builtin_amdgcn_mfma_f32_16x16x32_bf16(ah[mf], bkl[nf], acck[mf][nf], 0, 0, 0);
        acck[mf][nf] =
            __builtin_amdgcn_mfma_f32_16x16x32_bf16(al[mf], bkh[nf], acck[mf][nf], 0, 0, 0);
        accv[mf][nf] =
            __builtin_amdgcn_mfma_f32_16x16x32_bf16(ah[mf], bvh[nf], accv[mf][nf], 0, 0, 0);
      }
    __syncthreads();
  }

#pragma unroll
  for (int mf = 0; mf < 4; ++mf)
#pragma unroll
    for (int r = 0; r < 4; ++r) {
      int m = m0 + wy * 64 + mf * 16 + (l >> 4) * 4 + r;
#pragma unroll
      for (int nf = 0; nf < 4; ++nf) {
        int n = n0 + wx * 64 + nf * 16 + lrow;
        size_t off = ((size_t)b * TT + m) * CC + n;
        kout[off] = acck[mf][nf][r];
        vout[off] = bf16_rn(accv[mf][nf][r]);
      }
    }
}

// ---------------------------------------------------------------------------
// sim (bf16-split MFMA, no store) + per-block per-token top-3 candidates.
// (256 threads, unchanged.)
// ---------------------------------------------------------------------------
__global__ __launch_bounds__(256) void mfma_sim_top3(
    const float* __restrict__ q, const float* __restrict__ kb,
    unsigned long long* __restrict__ cand1, unsigned long long* __restrict__ cand2,
    unsigned long long* __restrict__ cand3) {
  __shared__ unsigned short Ah[128][40], Al[128][40], Bh[128][40], Bl[128][40];
  __shared__ unsigned long long c1[128], c2[128], c3[128];

  const int b = blockIdx.z;
  const float* A = q + (size_t)b * NNODE * CC;
  const float* Bm = kb + (size_t)b * TT * CC;
  const int n0 = blockIdx.y * 128;  // nodes
  const int t0 = blockIdx.x * 128;  // tokens
  const int tid = threadIdx.x;
  const int l = tid & 63;
  const int wid = tid >> 6;
  const int wy = wid >> 1, wx = wid & 1;
  const int lrow = l & 15, lkb = (l >> 4) * 8;

  if (tid < 128) { c1[tid] = 0ULL; c2[tid] = 0ULL; c3[tid] = 0ULL; }

  f32x4 acc[4][4] = {};

  for (int k0 = 0; k0 < CC; k0 += 32) {
    {
      int r = tid >> 3, c = (tid & 7) * 4;
#pragma unroll
      for (int p = 0; p < 4; ++p, r += 32) {
        float4v v = *(const float4v*)(A + (size_t)(n0 + r) * CC + k0 + c);
        float4v w = *(const float4v*)(Bm + (size_t)(t0 + r) * CC + k0 + c);
#pragma unroll
        for (int i = 0; i < 4; ++i) {
          unsigned short h = bf16_rn(v[i]);
          Ah[r][c + i] = h;
          Al[r][c + i] = bf16_rn(v[i] - bf16_tof(h));
          unsigned short hb = bf16_rn(w[i]);
          Bh[r][c + i] = hb;
          Bl[r][c + i] = bf16_rn(w[i] - bf16_tof(hb));
        }
      }
    }
    __syncthreads();

    bf16x8 ah[4], al[4], bh[4], bl[4];
#pragma unroll
    for (int mf = 0; mf < 4; ++mf) {
      ah[mf] = *(const bf16x8*)&Ah[wy * 64 + mf * 16 + lrow][lkb];
      al[mf] = *(const bf16x8*)&Al[wy * 64 + mf * 16 + lrow][lkb];
    }
#pragma unroll
    for (int nf = 0; nf < 4; ++nf) {
      bh[nf] = *(const bf16x8*)&Bh[wx * 64 + nf * 16 + lrow][lkb];
      bl[nf] = *(const bf16x8*)&Bl[wx * 64 + nf * 16 + lrow][lkb];
    }
#pragma unroll
    for (int mf = 0; mf < 4; ++mf)
#pragma unroll
      for (int nf = 0; nf < 4; ++nf) {
        acc[mf][nf] =
            __builtin_amdgcn_mfma_f32_16x16x32_bf16(ah[mf], bh[nf], acc[mf][nf], 0, 0, 0);
        acc[mf][nf] =
            __builtin_amdgcn_mfma_f32_16x16x32_bf16(ah[mf], bl[nf], acc[mf][nf], 0, 0, 0);
        acc[mf][nf] =
            __builtin_amdgcn_mfma_f32_16x16x32_bf16(al[mf], bh[nf], acc[mf][nf], 0, 0, 0);
      }
    __syncthreads();
  }

  const float scl = 0.04419417382415922f;
#pragma unroll
  for (int nf = 0; nf < 4; ++nf) {
    int tcol = wx * 64 + nf * 16 + lrow;
    unsigned long long m = 0ULL;
#pragma unroll
    for (int mf = 0; mf < 4; ++mf)
#pragma unroll
      for (int r = 0; r < 4; ++r) {
        unsigned node = (unsigned)(n0 + wy * 64 + mf * 16 + (l >> 4) * 4 + r);
        unsigned long long pk =
            ((unsigned long long)fkey(acc[mf][nf][r] * scl) << 32) | node;
        if (pk > m) m = pk;
      }
    atomicMax(&c1[tcol], m);
  }
  __syncthreads();
#pragma unroll
  for (int nf = 0; nf < 4; ++nf) {
    int tcol = wx * 64 + nf * 16 + lrow;
    unsigned w1 = (unsigned)c1[tcol];
    unsigned long long m = 0ULL;
#pragma unroll
    for (int mf = 0; mf < 4; ++mf)
#pragma unroll
      for (int r = 0; r < 4; ++r) {
        unsigned node = (unsigned)(n0 + wy * 64 + mf * 16 + (l >> 4) * 4 + r);
        if (node == w1) continue;
        unsigned long long pk =
            ((unsigned long long)fkey(acc[mf][nf][r] * scl) << 32) | node;
        if (pk > m) m = pk;
      }
    if (m) atomicMax(&c2[tcol], m);
  }
  __syncthreads();
#pragma unroll
  for (int nf = 0; nf < 4; ++nf) {
    int tcol = wx * 64 + nf * 16 + lrow;
    unsigned w1 = (unsigned)c1[tcol];
    unsigned w2 = (unsigned)c2[tcol];
    unsigned long long m = 0ULL;
#pragma unroll
    for (int mf = 0; mf < 4; ++mf)
#pragma unroll
      for (int r = 0; r < 4; ++r) {
        unsigned node = (unsigned)(n0 + wy * 64 + mf * 16 + (l >> 4) * 4 + r);
        if (node == w1 || node == w2) continue;
        unsigned long long pk =
            ((unsigned long long)fkey(acc[mf][nf][r] * scl) << 32) | node;
        if (pk > m) m = pk;
      }
    if (m) atomicMax(&c3[tcol], m);
  }
  __syncthreads();
  if (tid < 128) {
    size_t base = ((size_t)b * TT + (t0 + tid)) * 8 + blockIdx.y;
    cand1[base] = c1[tid];
    cand2[base] = c2[tid];
    cand3[base] = c3[tid];
  }
}

__global__ __launch_bounds__(256) void fill_zero(unsigned* __restrict__ p, long long n) {
  long long i = (long long)blockIdx.x * 256 + threadIdx.x;
  long long stride = (long long)gridDim.x * 256;
  for (; i < n; i += stride) p[i] = 0u;
}

// 32x32 tile transpose: dst[c][r] = src[r][c].
__global__ __launch_bounds__(256) void transpose_kernel(
    const float* __restrict__ src, float* __restrict__ dst, int R, int C) {
  __shared__ float tile[32][33];
  int r0 = blockIdx.y * 32, c0 = blockIdx.x * 32;
  int tx = threadIdx.x & 31, ty = threadIdx.x >> 5;  // 32 x 8
#pragma unroll
  for (int i = 0; i < 4; ++i)
    tile[ty + i * 8][tx] = src[(size_t)(r0 + ty + i * 8) * C + c0 + tx];
  __syncthreads();
#pragma unroll
  for (int i = 0; i < 4; ++i)
    dst[(size_t)(c0 + ty + i * 8) * R + r0 + tx] = tile[tx][ty + i * 8];
}

// ---------------------------------------------------------------------------
// Merge 8x(top-3) -> global top1 + rivals within GAP_MARGIN -> FLAT flag list.
// ---------------------------------------------------------------------------
__global__ __launch_bounds__(256) void merge_flag_kernel(
    const unsigned long long* __restrict__ cand1,
    const unsigned long long* __restrict__ cand2,
    const unsigned long long* __restrict__ cand3,
    unsigned long long* __restrict__ amaxIdx,
    unsigned* __restrict__ gcount, unsigned* __restrict__ gflag,
    unsigned* __restrict__ clist) {
  int bt = blockIdx.x * 256 + threadIdx.x;  // [0, B*T)
  unsigned long long best = 0ULL;
#pragma unroll
  for (int nb = 0; nb < 8; ++nb) {
    unsigned long long v = cand1[(size_t)bt * 8 + nb];
    if (v > best) best = v;
  }
  amaxIdx[bt] = best;
  float v1 = fdec((unsigned)(best >> 32));
  float thr = v1 - GAP_MARGIN;
  unsigned bestnode = (unsigned)best;

  unsigned nodes[MAXC];
  int cnt = 0;
#pragma unroll
  for (int nb = 0; nb < 8; ++nb) {
    unsigned long long cs[3] = {cand1[(size_t)bt * 8 + nb], cand2[(size_t)bt * 8 + nb],
                                cand3[(size_t)bt * 8 + nb]};
#pragma unroll
    for (int s = 0; s < 3; ++s) {
      float v = fdec((unsigned)(cs[s] >> 32));
      unsigned nd = (unsigned)cs[s];
      if (v >= thr && nd != bestnode && cnt < MAXC) nodes[cnt++] = nd;
    }
  }
  if (cnt > 0) {
    unsigned p = atomicAdd(gcount, 1u);
    if (p < NSLOT) {
      gflag[p] = (unsigned)bt;
      clist[(size_t)bt * 8] = (unsigned)(cnt + 1);
      clist[(size_t)bt * 8 + 1] = bestnode;
      for (int i = 0; i < cnt; ++i) clist[(size_t)bt * 8 + 2 + i] = nodes[i];
    }
  }
}

// ---------------------------------------------------------------------------
// Recheck phase A: k64[fi][d] = sum_c x_t[c] * Wk[d][c]  (f64, exact).
// ---------------------------------------------------------------------------
__global__ __launch_bounds__(256) void recheck_k64(
    const float* __restrict__ x, const float* __restrict__ WkT,
    const unsigned* __restrict__ gcount, const unsigned* __restrict__ gflag,
    double* __restrict__ k64g) {
  __shared__ float xs[CC];
  __shared__ double kpart[64][4];

  const unsigned cnt = min(*gcount, (unsigned)NSLOT);
  const int slot = blockIdx.x >> 3;
  const int dchunk = blockIdx.x & 7;
  if ((unsigned)slot >= cnt) return;
  const int tid = threadIdx.x;

  unsigned bt = gflag[slot];
  int b = bt >> 11, t = bt & (TT - 1);
  const float* xr = x + ((size_t)b * TT + t) * CC;
  xs[tid] = xr[tid];
  xs[tid + 256] = xr[tid + 256];
  __syncthreads();

  const int d = dchunk * 64 + (tid & 63);
  const int part = tid >> 6;  // 4 parts x 128 c
  const int cbase = part * 128;
  double a0 = 0.0, a1 = 0.0;
#pragma unroll 8
  for (int i = 0; i < 64; ++i) {
    int c = cbase + 2 * i;
    a0 = fma((double)WkT[(size_t)c * CC + d], (double)xs[c], a0);
    a1 = fma((double)WkT[(size_t)(c + 1) * CC + d], (double)xs[c + 1], a1);
  }
  kpart[tid & 63][part] = a0 + a1;
  __syncthreads();
  if (tid < 64) {
    double s = (kpart[tid][0] + kpart[tid][1]) + (kpart[tid][2] + kpart[tid][3]);
    k64g[(size_t)slot * CC + dchunk * 64 + tid] = s;
  }
}

// ---------------------------------------------------------------------------
// Recheck phase B: z[fi][t'] = sum_c x[t'][c] * k64[fi][c]  (f64 acc, f32 out).
// ---------------------------------------------------------------------------
__global__ __launch_bounds__(256) void recheck_z(
    const float* __restrict__ x, const unsigned* __restrict__ gcount,
    const unsigned* __restrict__ gflag, const double* __restrict__ k64g,
    float* __restrict__ zg) {
  __shared__ float tile[64][129];  // 33 KB
  __shared__ double k64l[CC];      // 4 KB
  __shared__ double zp[64][4];     // 2 KB

  const unsigned cnt = min(*gcount, (unsigned)NSLOT);
  const int slot = blockIdx.x >> 5;
  const int tchunk = blockIdx.x & 31;
  if ((unsigned)slot >= cnt) return;
  const int tid = threadIdx.x;

  unsigned bt = gflag[slot];
  int b = bt >> 11;
  const float* xb = x + (size_t)b * TT * CC;
  const int tok0 = tchunk * 64;

  k64l[tid] = k64g[(size_t)slot * CC + tid];
  k64l[tid + 256] = k64g[(size_t)slot * CC + tid + 256];

  const int tok = tid >> 2;      // 64 tokens
  const int part = tid & 3;      // 4 c-parts of 32 per pass
  double z0 = 0.0, z1 = 0.0;

  for (int p = 0; p < 4; ++p) {
    __syncthreads();
    int c0 = p * 128;
#pragma unroll
    for (int j = 0; j < 32; ++j) {
      int lin = j * 256 + tid;
      int r = lin >> 7, col = lin & 127;
      tile[r][col] = xb[(size_t)(tok0 + r) * CC + c0 + col];
    }
    __syncthreads();
#pragma unroll
    for (int i = 0; i < 16; ++i) {
      int cl = part * 32 + 2 * i;
      z0 = fma((double)tile[tok][cl], k64l[c0 + cl], z0);
      z1 = fma((double)tile[tok][cl + 1], k64l[c0 + cl + 1], z1);
    }
  }
  zp[tok][part] = z0 + z1;
  __syncthreads();
  if (tid < 64) {
    double z = (zp[tid][0] + zp[tid][1]) + (zp[tid][2] + zp[tid][3]);
    zg[(size_t)slot * TT + tok0 + tid] = (float)z;
  }
}

// ---------------------------------------------------------------------------
// Recheck phase C: sim64(n) = Wq[n,:].z + bq[n]*sum(k64); argmax candidates.
// ---------------------------------------------------------------------------
__global__ __launch_bounds__(256) void recheck_cand(
    const float* __restrict__ Wq, const float* __restrict__ bq,
    const unsigned* __restrict__ gcount, const unsigned* __restrict__ gflag,
    const unsigned* __restrict__ clist, const double* __restrict__ k64g,
    const float* __restrict__ zg, unsigned long long* __restrict__ amaxIdx) {
  __shared__ double red[4];
  __shared__ double ssumS;

  const unsigned cnt = min(*gcount, (unsigned)NSLOT);
  const int slot = blockIdx.x;
  if ((unsigned)slot >= cnt) return;
  const int tid = threadIdx.x;

  unsigned bt = gflag[slot];

  // ssum = sum(k64)
  double ps = k64g[(size_t)slot * CC + tid] + k64g[(size_t)slot * CC + tid + 256];
#pragma unroll
  for (int off = 32; off > 0; off >>= 1) ps += __shfl_down(ps, off, 64);
  if ((tid & 63) == 0) red[tid >> 6] = ps;
  __syncthreads();
  if (tid == 0) ssumS = (red[0] + red[1]) + (red[2] + red[3]);
  __syncthreads();
  const double ssum = ssumS;

  const double scl = 0.04419417382415922;
  unsigned ncand = clist[(size_t)bt * 8];
  unsigned long long bestpk = 0ULL;
  double bestv = -1e300;
  for (unsigned ci = 0; ci < ncand; ++ci) {
    unsigned n = clist[(size_t)bt * 8 + 1 + ci];
    const float* wq = Wq + (size_t)n * TT;
    const float* zr = zg + (size_t)slot * TT;
    double a = 0.0;
#pragma unroll
    for (int i = 0; i < TT / 256; ++i) {
      int tp = tid + i * 256;
      a = fma((double)wq[tp], (double)zr[tp], a);
    }
#pragma unroll
    for (int off = 32; off > 0; off >>= 1) a += __shfl_down(a, off, 64);
    if ((tid & 63) == 0) red[tid >> 6] = a;
    __syncthreads();
    double s = ((red[0] + red[1]) + (red[2] + red[3])) + (double)bq[n] * ssum;
    if (s > bestv) {
      bestv = s;
      bestpk = ((unsigned long long)fkey((float)(s * scl)) << 32) | n;
    }
    __syncthreads();
  }
  if (tid == 0) amaxIdx[bt] = bestpk;
}

__global__ __launch_bounds__(256) void node_max_kernel(
    const unsigned long long* __restrict__ amaxIdx, unsigned* __restrict__ Mpack) {
  int i = blockIdx.x * 256 + threadIdx.x;
  unsigned long long pk = amaxIdx[i];
  int b = i >> 11;
  unsigned w = (unsigned)pk;
  atomicMax(&Mpack[b * NNODE + w], (unsigned)(pk >> 32));
}

__global__ __launch_bounds__(256) void node_denom_kernel(
    const unsigned long long* __restrict__ amaxIdx, const unsigned* __restrict__ Mpack,
    float* __restrict__ D, float* __restrict__ att_val) {
  int i = blockIdx.x * 256 + threadIdx.x;
  unsigned long long pk = amaxIdx[i];
  int b = i >> 11;
  unsigned w = (unsigned)pk;
  float amaxf = fdec((unsigned)(pk >> 32));
  float Mf = fdec(Mpack[b * NNODE + w]);
  float e = expf(amaxf - Mf);
  att_val[i] = e;
  atomicAdd(&D[b * NNODE + w], e);
}

__global__ __launch_bounds__(256) void att_write_kernel(
    const unsigned long long* __restrict__ amaxIdx, const float* __restrict__ D,
    float* __restrict__ att_val, float* __restrict__ att_out) {
  int i = blockIdx.x * 256 + threadIdx.x;
  unsigned long long pk = amaxIdx[i];
  int b = i >> 11;
  int t = i & (TT - 1);
  unsigned w = (unsigned)pk;
  float a = att_val[i] / D[b * NNODE + w];
  att_val[i] = a;
  att_out[((size_t)b * NNODE + w) * TT + t] = a;
}

__global__ __launch_bounds__(256) void pv_scatter_kernel(
    const unsigned long long* __restrict__ amaxIdx, const float* __restrict__ att_val,
    const unsigned short* __restrict__ v, float* __restrict__ out0) {
  int bt = blockIdx.x;  // [0, B*T)
  int b = bt >> 11;
  float a = att_val[bt];
  unsigned w = (unsigned)amaxIdx[bt];
  const unsigned short* vr = v + (size_t)bt * CC;
  float* orow = out0 + ((size_t)b * NNODE + w) * CC;
  for (int c = threadIdx.x; c < CC; c += 256)
    atomicAdd(&orow[c], a * bf16_tof(vr[c]));
}

extern "C" void kernel_launch(void* const* d_in, const int* in_sizes, int n_in,
                              void* d_out, int out_size, void* d_ws, size_t ws_size,
                              hipStream_t stream) {
  const float* x = (const float*)d_in[0];     // [B,T,C]  f32
  const float* Wq = (const float*)d_in[1];    // [N,T]
  const float* bq = (const float*)d_in[2];    // [N]
  const float* Wk = (const float*)d_in[3];    // [C,C]
  const float* Wv = (const float*)d_in[4];    // [C,C]
  const float* Wout = (const float*)d_in[5];  // [C,C]
  const float* bout = (const float*)d_in[6];  // [C]

  float* out = (float*)d_out;                      // [B,N,C] f32
  float* att_out = out + (size_t)BB * NNODE * CC;  // [B,N,T] f32

  // Workspace layout (f32 word units), ~75 MB total.
  float* ws = (float*)d_ws;
  float* q = ws;                                // B*N*C f32 (reused as out0)
  float* kbuf = q + (size_t)BB * NNODE * CC;    // B*T*C f32
  unsigned short* vbuf = (unsigned short*)(kbuf + (size_t)BB * TT * CC);  // bf16 bits
  unsigned long long* cand1 =
      (unsigned long long*)((unsigned*)vbuf + (size_t)BB * TT * CC / 2);  // B*T*8 u64
  unsigned long long* cand2 = cand1 + (size_t)BB * TT * 8;
  unsigned long long* cand3 = cand2 + (size_t)BB * TT * 8;
  unsigned long long* amaxIdx = cand3 + (size_t)BB * TT * 8;              // B*T u64
  unsigned* Mpack = (unsigned*)(amaxIdx + (size_t)BB * TT);               // B*N u32
  float* D = (float*)(Mpack + (size_t)BB * NNODE);                        // B*N f32
  unsigned* counts = (unsigned*)(D + (size_t)BB * NNODE);                 // 16 u32 (gcount)
  float* att_val = (float*)(counts + 16);                                 // B*T f32
  unsigned* gflag = (unsigned*)(att_val + (size_t)BB * TT);               // B*T u32
  unsigned* clist = gflag + (size_t)BB * TT;                              // B*T*8 u32
  float* WkT = (float*)(clist + (size_t)BB * TT * 8);                     // C*C f32
  double* k64g = (double*)(WkT + (size_t)CC * CC);                        // NSLOT*C f64
  float* zg = (float*)(k64g + (size_t)NSLOT * CC);                        // NSLOT*T f32
  float* out0 = q;

  dim3 blk(256);
  dim3 blk512(512);

  // Z1: zero Mpack | D | counts (contiguous)
  fill_zero<<<dim3(64), blk, 0, stream>>>(Mpack, (long long)BB * NNODE * 2 + 16);
  // Z2: zero att region of d_out
  fill_zero<<<dim3(4096), blk, 0, stream>>>((unsigned*)att_out,
                                            (long long)BB * NNODE * TT);

  // WkT[c][d] = Wk[d][c]  (for coalesced recheck k64)
  transpose_kernel<<<dim3(CC / 32, CC / 32), blk, 0, stream>>>(Wk, WkT, CC, CC);

  // q[b,n,c] = sum_t Wq[n,t] x[b,t,c] + bq[n]  (bf16-split MFMA, 8 waves)
  mfma_gemm<true, false, 1><<<dim3(CC / 128, NNODE / 128, BB), blk512, 0, stream>>>(
      Wq, x, q, bq, TT, TT, CC, CC, 0LL, (long long)TT * CC,
      (long long)NNODE * CC, 1.0f);

  // fused k (split, f32) + v (plain, bf16)
  mfma_kv<<<dim3(CC / 128, TT / 128, BB), blk, 0, stream>>>(x, Wk, Wv, kbuf, vbuf);

  // sim (split MFMA) + per-block top-3 candidates
  mfma_sim_top3<<<dim3(TT / 128, NNODE / 128, BB), blk, 0, stream>>>(
      q, kbuf, cand1, cand2, cand3);

  // merge -> amaxIdx + flat flag list + candidate lists
  merge_flag_kernel<<<dim3(BB * TT / 256), blk, 0, stream>>>(
      cand1, cand2, cand3, amaxIdx, counts, gflag, clist);

  // exact f64 recheck: 3 phase-parallel kernels
  recheck_k64<<<dim3(NSLOT * 8), blk, 0, stream>>>(x, WkT, counts, gflag, k64g);
  recheck_z<<<dim3(NSLOT * 32), blk, 0, stream>>>(x, counts, gflag, k64g, zg);
  recheck_cand<<<dim3(NSLOT), blk, 0, stream>>>(Wq, bq, counts, gflag, clist,
                                                k64g, zg, amaxIdx);

  // zero out0 (aliases q; q dead after sim)
  fill_zero<<<dim3(2048), blk, 0, stream>>>((unsigned*)out0, (long long)BB * NNODE * CC);

  node_max_kernel<<<dim3(BB * TT / 256), blk, 0, stream>>>(amaxIdx, Mpack);
  node_denom_kernel<<<dim3(BB * TT / 256), blk, 0, stream>>>(amaxIdx, Mpack, D, att_val);
  att_write_kernel<<<dim3(BB * TT / 256), blk, 0, stream>>>(amaxIdx, D, att_val, att_out);

  // sparse PV scatter: out0[b,w,c] += att * v[b,t,c]
  pv_scatter_kernel<<<dim3(BB * TT), blk, 0, stream>>>(amaxIdx, att_val, vbuf, out0);

  // out[b,n,d] = sum_c out0[b,n,c] Wout[d,c] + bout[d]  (plain MFMA, 8 waves)
  mfma_gemm<false, true, 2><<<dim3(CC / 128, BB * NNODE / 128, 1), blk512, 0, stream>>>(
      out0, Wout, out, bout, CC, CC, CC, CC, 0LL, 0LL, 0LL, 1.0f);
}

// Round 15
// 427.094 us; speedup vs baseline: 1.9093x; 1.0164x over previous
//
#include <hip/hip_runtime.h>
#include <hip/hip_bf16.h>
#include <cfloat>

// Problem constants
#define BB 8
#define TT 2048
#define CC 512
#define NNODE 1024

#define GAP_MARGIN 2e-4f  // screening margin (~40 sigma of bf16-split screen noise)
#define MAXC 6            // max rival candidates per flagged token
#define NSLOT 512         // recheck flag capacity

typedef float f32x4 __attribute__((ext_vector_type(4)));
typedef short bf16x8 __attribute__((ext_vector_type(8)));
typedef float float4v __attribute__((ext_vector_type(4)));
typedef unsigned short u16x4 __attribute__((ext_vector_type(4)));
typedef unsigned short u16x8 __attribute__((ext_vector_type(8)));

// ---------------------------------------------------------------------------
__device__ __forceinline__ unsigned fkey(float v) {
  unsigned u = __float_as_uint(v);
  return (u & 0x80000000u) ? ~u : (u | 0x80000000u);
}
__device__ __forceinline__ float fdec(unsigned k) {
  unsigned u = (k & 0x80000000u) ? (k & 0x7FFFFFFFu) : ~k;
  return __uint_as_float(u);
}
__device__ __forceinline__ unsigned short bf16_rn(float f) {
  unsigned u = __float_as_uint(f);
  u += 0x7FFFu + ((u >> 16) & 1u);
  return (unsigned short)(u >> 16);
}
__device__ __forceinline__ float bf16_tof(unsigned short h) {
  return __uint_as_float(((unsigned)h) << 16);
}

// ---------------------------------------------------------------------------
// Pre-split kernels: f32 -> bf16 hi (+ lo residual), vectorized x4.
// ---------------------------------------------------------------------------
__global__ __launch_bounds__(256) void split2_kernel(
    const float* __restrict__ src, unsigned short* __restrict__ hi,
    unsigned short* __restrict__ lo, long long n4) {
  long long i = (long long)blockIdx.x * 256 + threadIdx.x;
  long long stride = (long long)gridDim.x * 256;
  for (; i < n4; i += stride) {
    float4v v = ((const float4v*)src)[i];
    u16x4 h, l;
#pragma unroll
    for (int j = 0; j < 4; ++j) {
      unsigned short hh = bf16_rn(v[j]);
      h[j] = hh;
      l[j] = bf16_rn(v[j] - bf16_tof(hh));
    }
    ((u16x4*)hi)[i] = h;
    ((u16x4*)lo)[i] = l;
  }
}

__global__ __launch_bounds__(256) void split1_kernel(
    const float* __restrict__ src, unsigned short* __restrict__ hi, long long n4) {
  long long i = (long long)blockIdx.x * 256 + threadIdx.x;
  long long stride = (long long)gridDim.x * 256;
  for (; i < n4; i += stride) {
    float4v v = ((const float4v*)src)[i];
    u16x4 h;
#pragma unroll
    for (int j = 0; j < 4; ++j) h[j] = bf16_rn(v[j]);
    ((u16x4*)hi)[i] = h;
  }
}

// ---------------------------------------------------------------------------
// q GEMM (pre-split inputs, 512 threads, 8 waves 2Mx4N, 128x128 tile, BK=32):
// q[b,m,n] = sum_t Wq[m,t]*x[b,t,n] + bq[m]; writes qh/ql (bf16 split).
// Staging: A = pure u16x8 copies; B = transpose staging (coalesced u16 reads).
// ---------------------------------------------------------------------------
__global__ __launch_bounds__(512) void mfma_q(
    const unsigned short* __restrict__ Wqh, const unsigned short* __restrict__ Wql,
    const unsigned short* __restrict__ xh, const unsigned short* __restrict__ xl,
    const float* __restrict__ bq,
    unsigned short* __restrict__ qh, unsigned short* __restrict__ ql) {
  __shared__ unsigned short Ah[128][40], Al[128][40], Bh[128][40], Bl[128][40];

  const int b = blockIdx.z;
  const unsigned short* xhb = xh + (size_t)b * TT * CC;
  const unsigned short* xlb = xl + (size_t)b * TT * CC;
  const int m0 = blockIdx.y * 128;  // nodes
  const int n0 = blockIdx.x * 128;  // c
  const int tid = threadIdx.x;
  const int l = tid & 63;
  const int wid = tid >> 6;
  const int wy = wid >> 2, wx = wid & 3;
  const int lrow = l & 15, lkb = (l >> 4) * 8;
  const int nn = tid & 127, kq = tid >> 7;  // B transpose assignment
  const int ar = tid >> 2, ack = (tid & 3) * 8;  // A copy assignment

  f32x4 acc[4][2] = {};

  for (int k0 = 0; k0 < TT; k0 += 32) {
    *(u16x8*)&Ah[ar][ack] = *(const u16x8*)(Wqh + (size_t)(m0 + ar) * TT + k0 + ack);
    *(u16x8*)&Al[ar][ack] = *(const u16x8*)(Wql + (size_t)(m0 + ar) * TT + k0 + ack);
    {
      u16x8 hv, lv;
#pragma unroll
      for (int j = 0; j < 8; ++j) {
        size_t gi = (size_t)(k0 + kq * 8 + j) * CC + n0 + nn;
        hv[j] = xhb[gi];
        lv[j] = xlb[gi];
      }
      *(u16x8*)&Bh[nn][kq * 8] = hv;
      *(u16x8*)&Bl[nn][kq * 8] = lv;
    }
    __syncthreads();

    bf16x8 ah[4], al[4], bh[2], bl[2];
#pragma unroll
    for (int mf = 0; mf < 4; ++mf) {
      ah[mf] = *(const bf16x8*)&Ah[wy * 64 + mf * 16 + lrow][lkb];
      al[mf] = *(const bf16x8*)&Al[wy * 64 + mf * 16 + lrow][lkb];
    }
#pragma unroll
    for (int nf = 0; nf < 2; ++nf) {
      bh[nf] = *(const bf16x8*)&Bh[wx * 32 + nf * 16 + lrow][lkb];
      bl[nf] = *(const bf16x8*)&Bl[wx * 32 + nf * 16 + lrow][lkb];
    }
#pragma unroll
    for (int mf = 0; mf < 4; ++mf)
#pragma unroll
      for (int nf = 0; nf < 2; ++nf) {
        acc[mf][nf] =
            __builtin_amdgcn_mfma_f32_16x16x32_bf16(ah[mf], bh[nf], acc[mf][nf], 0, 0, 0);
        acc[mf][nf] =
            __builtin_amdgcn_mfma_f32_16x16x32_bf16(ah[mf], bl[nf], acc[mf][nf], 0, 0, 0);
        acc[mf][nf] =
            __builtin_amdgcn_mfma_f32_16x16x32_bf16(al[mf], bh[nf], acc[mf][nf], 0, 0, 0);
      }
    __syncthreads();
  }

#pragma unroll
  for (int mf = 0; mf < 4; ++mf)
#pragma unroll
    for (int r = 0; r < 4; ++r) {
      int m = m0 + wy * 64 + mf * 16 + (l >> 4) * 4 + r;
      float bias = bq[m];
#pragma unroll
      for (int nf = 0; nf < 2; ++nf) {
        int n = n0 + wx * 32 + nf * 16 + lrow;
        float v = acc[mf][nf][r] + bias;
        size_t off = ((size_t)b * NNODE + m) * CC + n;
        unsigned short h = bf16_rn(v);
        qh[off] = h;
        ql[off] = bf16_rn(v - bf16_tof(h));
      }
    }
}

// ---------------------------------------------------------------------------
// Fused k (split) + v (plain) projection from pre-split inputs (256 threads).
// k[b,t,d] = sum_c x[b,t,c]*Wk[d,c] -> kh/kl;  v -> vbuf (bf16).
// ---------------------------------------------------------------------------
__global__ __launch_bounds__(256) void mfma_kv_pre(
    const unsigned short* __restrict__ xh, const unsigned short* __restrict__ xl,
    const unsigned short* __restrict__ Wkh, const unsigned short* __restrict__ Wkl,
    const unsigned short* __restrict__ Wvh,
    unsigned short* __restrict__ kh, unsigned short* __restrict__ kl,
    unsigned short* __restrict__ vout) {
  __shared__ unsigned short Ah[128][40], Al[128][40], Bkh[128][40], Bkl[128][40],
      Bvh[128][40];

  const int b = blockIdx.z;
  const unsigned short* xhb = xh + (size_t)b * TT * CC;
  const unsigned short* xlb = xl + (size_t)b * TT * CC;
  const int m0 = blockIdx.y * 128;  // tokens
  const int n0 = blockIdx.x * 128;  // out dim
  const int tid = threadIdx.x;
  const int l = tid & 63;
  const int wid = tid >> 6;
  const int wy = wid >> 1, wx = wid & 1;
  const int lrow = l & 15, lkb = (l >> 4) * 8;

  f32x4 acck[4][4] = {}, accv[4][4] = {};

  for (int k0 = 0; k0 < CC; k0 += 32) {
#pragma unroll
    for (int p = 0; p < 2; ++p) {
      int idx = tid + p * 256;
      int r = idx >> 2, ck = (idx & 3) * 8;
      *(u16x8*)&Ah[r][ck] = *(const u16x8*)(xhb + (size_t)(m0 + r) * CC + k0 + ck);
      *(u16x8*)&Al[r][ck] = *(const u16x8*)(xlb + (size_t)(m0 + r) * CC + k0 + ck);
      *(u16x8*)&Bkh[r][ck] = *(const u16x8*)(Wkh + (size_t)(n0 + r) * CC + k0 + ck);
      *(u16x8*)&Bkl[r][ck] = *(const u16x8*)(Wkl + (size_t)(n0 + r) * CC + k0 + ck);
      *(u16x8*)&Bvh[r][ck] = *(const u16x8*)(Wvh + (size_t)(n0 + r) * CC + k0 + ck);
    }
    __syncthreads();

    bf16x8 ah[4], al[4], bkh4[4], bkl4[4], bvh4[4];
#pragma unroll
    for (int mf = 0; mf < 4; ++mf) {
      ah[mf] = *(const bf16x8*)&Ah[wy * 64 + mf * 16 + lrow][lkb];
      al[mf] = *(const bf16x8*)&Al[wy * 64 + mf * 16 + lrow][lkb];
    }
#pragma unroll
    for (int nf = 0; nf < 4; ++nf) {
      bkh4[nf] = *(const bf16x8*)&Bkh[wx * 64 + nf * 16 + lrow][lkb];
      bkl4[nf] = *(const bf16x8*)&Bkl[wx * 64 + nf * 16 + lrow][lkb];
      bvh4[nf] = *(const bf16x8*)&Bvh[wx * 64 + nf * 16 + lrow][lkb];
    }
#pragma unroll
    for (int mf = 0; mf < 4; ++mf)
#pragma unroll
      for (int nf = 0; nf < 4; ++nf) {
        acck[mf][nf] =
            __builtin_amdgcn_mfma_f32_16x16x32_bf16(ah[mf], bkh4[nf], acck[mf][nf], 0, 0, 0);
        acck[mf][nf] =
            __builtin_amdgcn_mfma_f32_16x16x32_bf16(ah[mf], bkl4[nf], acck[mf][nf], 0, 0, 0);
        acck[mf][nf] =
            __builtin_amdgcn_mfma_f32_16x16x32_bf16(al[mf], bkh4[nf], acck[mf][nf], 0, 0, 0);
        accv[mf][nf] =
            __builtin_amdgcn_mfma_f32_16x16x32_bf16(ah[mf], bvh4[nf], accv[mf][nf], 0, 0, 0);
      }
    __syncthreads();
  }

#pragma unroll
  for (int mf = 0; mf < 4; ++mf)
#pragma unroll
    for (int r = 0; r < 4; ++r) {
      int m = m0 + wy * 64 + mf * 16 + (l >> 4) * 4 + r;
#pragma unroll
      for (int nf = 0; nf < 4; ++nf) {
        int n = n0 + wx * 64 + nf * 16 + lrow;
        size_t off = ((size_t)b * TT + m) * CC + n;
        float kvv = acck[mf][nf][r];
        unsigned short h = bf16_rn(kvv);
        kh[off] = h;
        kl[off] = bf16_rn(kvv - bf16_tof(h));
        vout[off] = bf16_rn(accv[mf][nf][r]);
      }
    }
}

// ---------------------------------------------------------------------------
// sim (pre-split q,k; no store) + per-block per-token top-3 candidates.
// ---------------------------------------------------------------------------
__global__ __launch_bounds__(256) void mfma_sim_pre(
    const unsigned short* __restrict__ qh, const unsigned short* __restrict__ ql,
    const unsigned short* __restrict__ kh, const unsigned short* __restrict__ kl,
    unsigned long long* __restrict__ cand1, unsigned long long* __restrict__ cand2,
    unsigned long long* __restrict__ cand3) {
  __shared__ unsigned short Ah[128][40], Al[128][40], Bh[128][40], Bl[128][40];
  __shared__ unsigned long long c1[128], c2[128], c3[128];

  const int b = blockIdx.z;
  const unsigned short* qhb = qh + (size_t)b * NNODE * CC;
  const unsigned short* qlb = ql + (size_t)b * NNODE * CC;
  const unsigned short* khb = kh + (size_t)b * TT * CC;
  const unsigned short* klb = kl + (size_t)b * TT * CC;
  const int n0 = blockIdx.y * 128;  // nodes
  const int t0 = blockIdx.x * 128;  // tokens
  const int tid = threadIdx.x;
  const int l = tid & 63;
  const int wid = tid >> 6;
  const int wy = wid >> 1, wx = wid & 1;
  const int lrow = l & 15, lkb = (l >> 4) * 8;

  if (tid < 128) { c1[tid] = 0ULL; c2[tid] = 0ULL; c3[tid] = 0ULL; }

  f32x4 acc[4][4] = {};

  for (int k0 = 0; k0 < CC; k0 += 32) {
#pragma unroll
    for (int p = 0; p < 2; ++p) {
      int idx = tid + p * 256;
      int r = idx >> 2, ck = (idx & 3) * 8;
      *(u16x8*)&Ah[r][ck] = *(const u16x8*)(qhb + (size_t)(n0 + r) * CC + k0 + ck);
      *(u16x8*)&Al[r][ck] = *(const u16x8*)(qlb + (size_t)(n0 + r) * CC + k0 + ck);
      *(u16x8*)&Bh[r][ck] = *(const u16x8*)(khb + (size_t)(t0 + r) * CC + k0 + ck);
      *(u16x8*)&Bl[r][ck] = *(const u16x8*)(klb + (size_t)(t0 + r) * CC + k0 + ck);
    }
    __syncthreads();

    bf16x8 ah[4], al[4], bh[4], bl[4];
#pragma unroll
    for (int mf = 0; mf < 4; ++mf) {
      ah[mf] = *(const bf16x8*)&Ah[wy * 64 + mf * 16 + lrow][lkb];
      al[mf] = *(const bf16x8*)&Al[wy * 64 + mf * 16 + lrow][lkb];
    }
#pragma unroll
    for (int nf = 0; nf < 4; ++nf) {
      bh[nf] = *(const bf16x8*)&Bh[wx * 64 + nf * 16 + lrow][lkb];
      bl[nf] = *(const bf16x8*)&Bl[wx * 64 + nf * 16 + lrow][lkb];
    }
#pragma unroll
    for (int mf = 0; mf < 4; ++mf)
#pragma unroll
      for (int nf = 0; nf < 4; ++nf) {
        acc[mf][nf] =
            __builtin_amdgcn_mfma_f32_16x16x32_bf16(ah[mf], bh[nf], acc[mf][nf], 0, 0, 0);
        acc[mf][nf] =
            __builtin_amdgcn_mfma_f32_16x16x32_bf16(ah[mf], bl[nf], acc[mf][nf], 0, 0, 0);
        acc[mf][nf] =
            __builtin_amdgcn_mfma_f32_16x16x32_bf16(al[mf], bh[nf], acc[mf][nf], 0, 0, 0);
      }
    __syncthreads();
  }

  const float scl = 0.04419417382415922f;
#pragma unroll
  for (int nf = 0; nf < 4; ++nf) {
    int tcol = wx * 64 + nf * 16 + lrow;
    unsigned long long m = 0ULL;
#pragma unroll
    for (int mf = 0; mf < 4; ++mf)
#pragma unroll
      for (int r = 0; r < 4; ++r) {
        unsigned node = (unsigned)(n0 + wy * 64 + mf * 16 + (l >> 4) * 4 + r);
        unsigned long long pk =
            ((unsigned long long)fkey(acc[mf][nf][r] * scl) << 32) | node;
        if (pk > m) m = pk;
      }
    atomicMax(&c1[tcol], m);
  }
  __syncthreads();
#pragma unroll
  for (int nf = 0; nf < 4; ++nf) {
    int tcol = wx * 64 + nf * 16 + lrow;
    unsigned w1 = (unsigned)c1[tcol];
    unsigned long long m = 0ULL;
#pragma unroll
    for (int mf = 0; mf < 4; ++mf)
#pragma unroll
      for (int r = 0; r < 4; ++r) {
        unsigned node = (unsigned)(n0 + wy * 64 + mf * 16 + (l >> 4) * 4 + r);
        if (node == w1) continue;
        unsigned long long pk =
            ((unsigned long long)fkey(acc[mf][nf][r] * scl) << 32) | node;
        if (pk > m) m = pk;
      }
    if (m) atomicMax(&c2[tcol], m);
  }
  __syncthreads();
#pragma unroll
  for (int nf = 0; nf < 4; ++nf) {
    int tcol = wx * 64 + nf * 16 + lrow;
    unsigned w1 = (unsigned)c1[tcol];
    unsigned w2 = (unsigned)c2[tcol];
    unsigned long long m = 0ULL;
#pragma unroll
    for (int mf = 0; mf < 4; ++mf)
#pragma unroll
      for (int r = 0; r < 4; ++r) {
        unsigned node = (unsigned)(n0 + wy * 64 + mf * 16 + (l >> 4) * 4 + r);
        if (node == w1 || node == w2) continue;
        unsigned long long pk =
            ((unsigned long long)fkey(acc[mf][nf][r] * scl) << 32) | node;
        if (pk > m) m = pk;
      }
    if (m) atomicMax(&c3[tcol], m);
  }
  __syncthreads();
  if (tid < 128) {
    size_t base = ((size_t)b * TT + (t0 + tid)) * 8 + blockIdx.y;
    cand1[base] = c1[tid];
    cand2[base] = c2[tid];
    cand3[base] = c3[tid];
  }
}

// ---------------------------------------------------------------------------
// Wout GEMM (f32 inputs, plain bf16 MFMA, 512 threads):
// out[m,n] = sum_c out0[m,c]*Wout[n,c] + bout[n], M flattened = BB*NNODE.
// ---------------------------------------------------------------------------
__global__ __launch_bounds__(512) void mfma_wout(
    const float* __restrict__ A, const float* __restrict__ Bm,
    float* __restrict__ Cp, const float* __restrict__ bias) {
  __shared__ unsigned short Ah[128][40], Bh[128][40];
  const int m0 = blockIdx.y * 128;
  const int n0 = blockIdx.x * 128;
  const int tid = threadIdx.x;
  const int l = tid & 63;
  const int wid = tid >> 6;
  const int wy = wid >> 2, wx = wid & 3;
  const int lrow = l & 15, lkb = (l >> 4) * 8;

  f32x4 acc[4][2] = {};

  for (int k0 = 0; k0 < CC; k0 += 32) {
#pragma unroll
    for (int p = 0; p < 2; ++p) {
      int idx = tid + p * 512;
      int r = idx >> 3, c = (idx & 7) * 4;
      float4v va = *(const float4v*)(A + (size_t)(m0 + r) * CC + k0 + c);
      float4v vb = *(const float4v*)(Bm + (size_t)(n0 + r) * CC + k0 + c);
#pragma unroll
      for (int i = 0; i < 4; ++i) {
        Ah[r][c + i] = bf16_rn(va[i]);
        Bh[r][c + i] = bf16_rn(vb[i]);
      }
    }
    __syncthreads();

    bf16x8 ah[4], bh[2];
#pragma unroll
    for (int mf = 0; mf < 4; ++mf)
      ah[mf] = *(const bf16x8*)&Ah[wy * 64 + mf * 16 + lrow][lkb];
#pragma unroll
    for (int nf = 0; nf < 2; ++nf)
      bh[nf] = *(const bf16x8*)&Bh[wx * 32 + nf * 16 + lrow][lkb];
#pragma unroll
    for (int mf = 0; mf < 4; ++mf)
#pragma unroll
      for (int nf = 0; nf < 2; ++nf)
        acc[mf][nf] =
            __builtin_amdgcn_mfma_f32_16x16x32_bf16(ah[mf], bh[nf], acc[mf][nf], 0, 0, 0);
    __syncthreads();
  }

#pragma unroll
  for (int mf = 0; mf < 4; ++mf)
#pragma unroll
    for (int r = 0; r < 4; ++r) {
      int m = m0 + wy * 64 + mf * 16 + (l >> 4) * 4 + r;
#pragma unroll
      for (int nf = 0; nf < 2; ++nf) {
        int n = n0 + wx * 32 + nf * 16 + lrow;
        Cp[(size_t)m * CC + n] = acc[mf][nf][r] + bias[n];
      }
    }
}

__global__ __launch_bounds__(256) void fill_zero(unsigned* __restrict__ p, long long n) {
  long long i = (long long)blockIdx.x * 256 + threadIdx.x;
  long long stride = (long long)gridDim.x * 256;
  for (; i < n; i += stride) p[i] = 0u;
}

// 32x32 tile transpose: dst[c][r] = src[r][c].
__global__ __launch_bounds__(256) void transpose_kernel(
    const float* __restrict__ src, float* __restrict__ dst, int R, int C) {
  __shared__ float tile[32][33];
  int r0 = blockIdx.y * 32, c0 = blockIdx.x * 32;
  int tx = threadIdx.x & 31, ty = threadIdx.x >> 5;  // 32 x 8
#pragma unroll
  for (int i = 0; i < 4; ++i)
    tile[ty + i * 8][tx] = src[(size_t)(r0 + ty + i * 8) * C + c0 + tx];
  __syncthreads();
#pragma unroll
  for (int i = 0; i < 4; ++i)
    dst[(size_t)(c0 + ty + i * 8) * R + r0 + tx] = tile[tx][ty + i * 8];
}

// ---------------------------------------------------------------------------
// Merge 8x(top-3) -> global top1 + rivals within GAP_MARGIN -> FLAT flag list.
// ---------------------------------------------------------------------------
__global__ __launch_bounds__(256) void merge_flag_kernel(
    const unsigned long long* __restrict__ cand1,
    const unsigned long long* __restrict__ cand2,
    const unsigned long long* __restrict__ cand3,
    unsigned long long* __restrict__ amaxIdx,
    unsigned* __restrict__ gcount, unsigned* __restrict__ gflag,
    unsigned* __restrict__ clist) {
  int bt = blockIdx.x * 256 + threadIdx.x;  // [0, B*T)
  unsigned long long best = 0ULL;
#pragma unroll
  for (int nb = 0; nb < 8; ++nb) {
    unsigned long long v = cand1[(size_t)bt * 8 + nb];
    if (v > best) best = v;
  }
  amaxIdx[bt] = best;
  float v1 = fdec((unsigned)(best >> 32));
  float thr = v1 - GAP_MARGIN;
  unsigned bestnode = (unsigned)best;

  unsigned nodes[MAXC];
  int cnt = 0;
#pragma unroll
  for (int nb = 0; nb < 8; ++nb) {
    unsigned long long cs[3] = {cand1[(size_t)bt * 8 + nb], cand2[(size_t)bt * 8 + nb],
                                cand3[(size_t)bt * 8 + nb]};
#pragma unroll
    for (int s = 0; s < 3; ++s) {
      float v = fdec((unsigned)(cs[s] >> 32));
      unsigned nd = (unsigned)cs[s];
      if (v >= thr && nd != bestnode && cnt < MAXC) nodes[cnt++] = nd;
    }
  }
  if (cnt > 0) {
    unsigned p = atomicAdd(gcount, 1u);
    if (p < NSLOT) {
      gflag[p] = (unsigned)bt;
      clist[(size_t)bt * 8] = (unsigned)(cnt + 1);
      clist[(size_t)bt * 8 + 1] = bestnode;
      for (int i = 0; i < cnt; ++i) clist[(size_t)bt * 8 + 2 + i] = nodes[i];
    }
  }
}

// ---------------------------------------------------------------------------
// Recheck phase A: k64[fi][d] = sum_c x_t[c] * Wk[d][c]  (f64, exact).
// ---------------------------------------------------------------------------
__global__ __launch_bounds__(256) void recheck_k64(
    const float* __restrict__ x, const float* __restrict__ WkT,
    const unsigned* __restrict__ gcount, const unsigned* __restrict__ gflag,
    double* __restrict__ k64g) {
  __shared__ float xs[CC];
  __shared__ double kpart[64][4];

  const unsigned cnt = min(*gcount, (unsigned)NSLOT);
  const int slot = blockIdx.x >> 3;
  const int dchunk = blockIdx.x & 7;
  if ((unsigned)slot >= cnt) return;
  const int tid = threadIdx.x;

  unsigned bt = gflag[slot];
  int b = bt >> 11, t = bt & (TT - 1);
  const float* xr = x + ((size_t)b * TT + t) * CC;
  xs[tid] = xr[tid];
  xs[tid + 256] = xr[tid + 256];
  __syncthreads();

  const int d = dchunk * 64 + (tid & 63);
  const int part = tid >> 6;
  const int cbase = part * 128;
  double a0 = 0.0, a1 = 0.0;
#pragma unroll 8
  for (int i = 0; i < 64; ++i) {
    int c = cbase + 2 * i;
    a0 = fma((double)WkT[(size_t)c * CC + d], (double)xs[c], a0);
    a1 = fma((double)WkT[(size_t)(c + 1) * CC + d], (double)xs[c + 1], a1);
  }
  kpart[tid & 63][part] = a0 + a1;
  __syncthreads();
  if (tid < 64) {
    double s = (kpart[tid][0] + kpart[tid][1]) + (kpart[tid][2] + kpart[tid][3]);
    k64g[(size_t)slot * CC + dchunk * 64 + tid] = s;
  }
}

// ---------------------------------------------------------------------------
// Recheck phase B: z[fi][t'] = sum_c x[t'][c] * k64[fi][c]  (f64 acc, f32 out).
// ---------------------------------------------------------------------------
__global__ __launch_bounds__(256) void recheck_z(
    const float* __restrict__ x, const unsigned* __restrict__ gcount,
    const unsigned* __restrict__ gflag, const double* __restrict__ k64g,
    float* __restrict__ zg) {
  __shared__ float tile[64][129];
  __shared__ double k64l[CC];
  __shared__ double zp[64][4];

  const unsigned cnt = min(*gcount, (unsigned)NSLOT);
  const int slot = blockIdx.x >> 5;
  const int tchunk = blockIdx.x & 31;
  if ((unsigned)slot >= cnt) return;
  const int tid = threadIdx.x;

  unsigned bt = gflag[slot];
  int b = bt >> 11;
  const float* xb = x + (size_t)b * TT * CC;
  const int tok0 = tchunk * 64;

  k64l[tid] = k64g[(size_t)slot * CC + tid];
  k64l[tid + 256] = k64g[(size_t)slot * CC + tid + 256];

  const int tok = tid >> 2;
  const int part = tid & 3;
  double z0 = 0.0, z1 = 0.0;

  for (int p = 0; p < 4; ++p) {
    __syncthreads();
    int c0 = p * 128;
#pragma unroll
    for (int j = 0; j < 32; ++j) {
      int lin = j * 256 + tid;
      int r = lin >> 7, col = lin & 127;
      tile[r][col] = xb[(size_t)(tok0 + r) * CC + c0 + col];
    }
    __syncthreads();
#pragma unroll
    for (int i = 0; i < 16; ++i) {
      int cl = part * 32 + 2 * i;
      z0 = fma((double)tile[tok][cl], k64l[c0 + cl], z0);
      z1 = fma((double)tile[tok][cl + 1], k64l[c0 + cl + 1], z1);
    }
  }
  zp[tok][part] = z0 + z1;
  __syncthreads();
  if (tid < 64) {
    double z = (zp[tid][0] + zp[tid][1]) + (zp[tid][2] + zp[tid][3]);
    zg[(size_t)slot * TT + tok0 + tid] = (float)z;
  }
}

// ---------------------------------------------------------------------------
// Recheck phase C: sim64(n) = Wq[n,:].z + bq[n]*sum(k64); argmax candidates.
// ---------------------------------------------------------------------------
__global__ __launch_bounds__(256) void recheck_cand(
    const float* __restrict__ Wq, const float* __restrict__ bq,
    const unsigned* __restrict__ gcount, const unsigned* __restrict__ gflag,
    const unsigned* __restrict__ clist, const double* __restrict__ k64g,
    const float* __restrict__ zg, unsigned long long* __restrict__ amaxIdx) {
  __shared__ double red[4];
  __shared__ double ssumS;

  const unsigned cnt = min(*gcount, (unsigned)NSLOT);
  const int slot = blockIdx.x;
  if ((unsigned)slot >= cnt) return;
  const int tid = threadIdx.x;

  unsigned bt = gflag[slot];

  double ps = k64g[(size_t)slot * CC + tid] + k64g[(size_t)slot * CC + tid + 256];
#pragma unroll
  for (int off = 32; off > 0; off >>= 1) ps += __shfl_down(ps, off, 64);
  if ((tid & 63) == 0) red[tid >> 6] = ps;
  __syncthreads();
  if (tid == 0) ssumS = (red[0] + red[1]) + (red[2] + red[3]);
  __syncthreads();
  const double ssum = ssumS;

  const double scl = 0.04419417382415922;
  unsigned ncand = clist[(size_t)bt * 8];
  unsigned long long bestpk = 0ULL;
  double bestv = -1e300;
  for (unsigned ci = 0; ci < ncand; ++ci) {
    unsigned n = clist[(size_t)bt * 8 + 1 + ci];
    const float* wq = Wq + (size_t)n * TT;
    const float* zr = zg + (size_t)slot * TT;
    double a = 0.0;
#pragma unroll
    for (int i = 0; i < TT / 256; ++i) {
      int tp = tid + i * 256;
      a = fma((double)wq[tp], (double)zr[tp], a);
    }
#pragma unroll
    for (int off = 32; off > 0; off >>= 1) a += __shfl_down(a, off, 64);
    if ((tid & 63) == 0) red[tid >> 6] = a;
    __syncthreads();
    double s = ((red[0] + red[1]) + (red[2] + red[3])) + (double)bq[n] * ssum;
    if (s > bestv) {
      bestv = s;
      bestpk = ((unsigned long long)fkey((float)(s * scl)) << 32) | n;
    }
    __syncthreads();
  }
  if (tid == 0) amaxIdx[bt] = bestpk;
}

__global__ __launch_bounds__(256) void node_max_kernel(
    const unsigned long long* __restrict__ amaxIdx, unsigned* __restrict__ Mpack) {
  int i = blockIdx.x * 256 + threadIdx.x;
  unsigned long long pk = amaxIdx[i];
  int b = i >> 11;
  unsigned w = (unsigned)pk;
  atomicMax(&Mpack[b * NNODE + w], (unsigned)(pk >> 32));
}

__global__ __launch_bounds__(256) void node_denom_kernel(
    const unsigned long long* __restrict__ amaxIdx, const unsigned* __restrict__ Mpack,
    float* __restrict__ D, float* __restrict__ att_val) {
  int i = blockIdx.x * 256 + threadIdx.x;
  unsigned long long pk = amaxIdx[i];
  int b = i >> 11;
  unsigned w = (unsigned)pk;
  float amaxf = fdec((unsigned)(pk >> 32));
  float Mf = fdec(Mpack[b * NNODE + w]);
  float e = expf(amaxf - Mf);
  att_val[i] = e;
  atomicAdd(&D[b * NNODE + w], e);
}

__global__ __launch_bounds__(256) void att_write_kernel(
    const unsigned long long* __restrict__ amaxIdx, const float* __restrict__ D,
    float* __restrict__ att_val, float* __restrict__ att_out) {
  int i = blockIdx.x * 256 + threadIdx.x;
  unsigned long long pk = amaxIdx[i];
  int b = i >> 11;
  int t = i & (TT - 1);
  unsigned w = (unsigned)pk;
  float a = att_val[i] / D[b * NNODE + w];
  att_val[i] = a;
  att_out[((size_t)b * NNODE + w) * TT + t] = a;
}

__global__ __launch_bounds__(256) void pv_scatter_kernel(
    const unsigned long long* __restrict__ amaxIdx, const float* __restrict__ att_val,
    const unsigned short* __restrict__ v, float* __restrict__ out0) {
  int bt = blockIdx.x;  // [0, B*T)
  int b = bt >> 11;
  float a = att_val[bt];
  unsigned w = (unsigned)amaxIdx[bt];
  const unsigned short* vr = v + (size_t)bt * CC;
  float* orow = out0 + ((size_t)b * NNODE + w) * CC;
  for (int c = threadIdx.x; c < CC; c += 256)
    atomicAdd(&orow[c], a * bf16_tof(vr[c]));
}

extern "C" void kernel_launch(void* const* d_in, const int* in_sizes, int n_in,
                              void* d_out, int out_size, void* d_ws, size_t ws_size,
                              hipStream_t stream) {
  const float* x = (const float*)d_in[0];     // [B,T,C]  f32
  const float* Wq = (const float*)d_in[1];    // [N,T]
  const float* bq = (const float*)d_in[2];    // [N]
  const float* Wk = (const float*)d_in[3];    // [C,C]
  const float* Wv = (const float*)d_in[4];    // [C,C]
  const float* Wout = (const float*)d_in[5];  // [C,C]
  const float* bout = (const float*)d_in[6];  // [C]

  float* out = (float*)d_out;                      // [B,N,C] f32
  float* att_out = out + (size_t)BB * NNODE * CC;  // [B,N,T] f32

  // Workspace layout: ~111.5 MB total. R = xh/xl region reused post-kv.
  const size_t BNC = (size_t)BB * NNODE * CC;  // 4,194,304
  const size_t BTC = (size_t)BB * TT * CC;     // 8,388,608
  const size_t NT = (size_t)NNODE * TT;        // 2,097,152
  const size_t CC2 = (size_t)CC * CC;          // 262,144
  const size_t BT = (size_t)BB * TT;           // 16,384

  unsigned short* qh = (unsigned short*)d_ws;
  unsigned short* ql = qh + BNC;
  unsigned short* kh = ql + BNC;
  unsigned short* kl = kh + BTC;
  unsigned short* vbuf = kl + BTC;
  unsigned short* Wqh = vbuf + BTC;
  unsigned short* Wql = Wqh + NT;
  unsigned short* Wkh = Wql + NT;
  unsigned short* Wkl = Wkh + CC2;
  unsigned short* Wvh = Wkl + CC2;
  unsigned short* xh = Wvh + CC2;
  unsigned short* xl = xh + BTC;
  unsigned long long* amaxIdx = (unsigned long long*)(xl + BTC);
  unsigned* Mpack = (unsigned*)(amaxIdx + BT);
  float* D = (float*)(Mpack + (size_t)BB * NNODE);
  unsigned* gcount = (unsigned*)(D + (size_t)BB * NNODE);
  float* att_val = (float*)(gcount + 16);
  unsigned* gflag = (unsigned*)(att_val + BT);
  unsigned* clist = gflag + BT;
  // Region R overlays xh/xl (33.5 MB; used after kv; sub-ranges disjoint):
  float* out0 = (float*)xh;                                      // 16.8 MB
  unsigned long long* cand1 = (unsigned long long*)(out0 + BNC); // 1 MB x3
  unsigned long long* cand2 = cand1 + BT * 8;
  unsigned long long* cand3 = cand2 + BT * 8;
  float* WkT = (float*)(cand3 + BT * 8);                         // 1 MB
  double* k64g = (double*)(WkT + CC2);                           // 2 MB
  float* zg = (float*)(k64g + (size_t)NSLOT * CC);               // 4 MB

  dim3 blk(256);
  dim3 blk512(512);

  // Pre-split inputs to bf16 hi/lo (one-time; hot loops become pure copies)
  split2_kernel<<<dim3(2048), blk, 0, stream>>>(x, xh, xl, (long long)(BTC / 4));
  split2_kernel<<<dim3(1024), blk, 0, stream>>>(Wq, Wqh, Wql, (long long)(NT / 4));
  split2_kernel<<<dim3(256), blk, 0, stream>>>(Wk, Wkh, Wkl, (long long)(CC2 / 4));
  split1_kernel<<<dim3(256), blk, 0, stream>>>(Wv, Wvh, (long long)(CC2 / 4));

  // Z1: zero Mpack | D | gcount (contiguous)
  fill_zero<<<dim3(64), blk, 0, stream>>>(Mpack, (long long)BB * NNODE * 2 + 16);
  // Z2: zero att region of d_out
  fill_zero<<<dim3(4096), blk, 0, stream>>>((unsigned*)att_out,
                                            (long long)BB * NNODE * TT);

  // q (bf16-split MFMA, pre-split inputs) -> qh/ql
  mfma_q<<<dim3(CC / 128, NNODE / 128, BB), blk512, 0, stream>>>(
      Wqh, Wql, xh, xl, bq, qh, ql);

  // fused k (split) + v (plain) -> kh/kl, vbuf   [last use of xh/xl]
  mfma_kv_pre<<<dim3(CC / 128, TT / 128, BB), blk, 0, stream>>>(
      xh, xl, Wkh, Wkl, Wvh, kh, kl, vbuf);

  // WkT (in R; safe after kv)
  transpose_kernel<<<dim3(CC / 32, CC / 32), blk, 0, stream>>>(Wk, WkT, CC, CC);

  // sim + top-3 candidates (pure-copy staging) -> cand1..3 (in R)
  mfma_sim_pre<<<dim3(TT / 128, NNODE / 128, BB), blk, 0, stream>>>(
      qh, ql, kh, kl, cand1, cand2, cand3);

  // merge -> amaxIdx + flat flag list + candidate lists
  merge_flag_kernel<<<dim3(BB * TT / 256), blk, 0, stream>>>(
      cand1, cand2, cand3, amaxIdx, gcount, gflag, clist);

  // exact f64 recheck: 3 phase-parallel kernels
  recheck_k64<<<dim3(NSLOT * 8), blk, 0, stream>>>(x, WkT, gcount, gflag, k64g);
  recheck_z<<<dim3(NSLOT * 32), blk, 0, stream>>>(x, gcount, gflag, k64g, zg);
  recheck_cand<<<dim3(NSLOT), blk, 0, stream>>>(Wq, bq, gcount, gflag, clist,
                                                k64g, zg, amaxIdx);

  // zero out0 (in R, disjoint from cand/WkT/k64g/zg)
  fill_zero<<<dim3(2048), blk, 0, stream>>>((unsigned*)out0, (long long)BB * NNODE * CC);

  node_max_kernel<<<dim3(BB * TT / 256), blk, 0, stream>>>(amaxIdx, Mpack);
  node_denom_kernel<<<dim3(BB * TT / 256), blk, 0, stream>>>(amaxIdx, Mpack, D, att_val);
  att_write_kernel<<<dim3(BB * TT / 256), blk, 0, stream>>>(amaxIdx, D, att_val, att_out);

  // sparse PV scatter: out0[b,w,c] += att * v[b,t,c]
  pv_scatter_kernel<<<dim3(BB * TT), blk, 0, stream>>>(amaxIdx, att_val, vbuf, out0);

  // out = out0 . Wout^T + bout  (plain MFMA, flattened M)
  mfma_wout<<<dim3(CC / 128, BB * NNODE / 128), blk512, 0, stream>>>(
      out0, Wout, out, bout);
}

// Round 16
// 389.821 us; speedup vs baseline: 2.0918x; 1.0956x over previous
//
#include <hip/hip_runtime.h>
#include <hip/hip_bf16.h>
#include <cfloat>

// Problem constants
#define BB 8
#define TT 2048
#define CC 512
#define NNODE 1024

#define GAP_MARGIN 2e-4f  // screening margin (~40 sigma of bf16-split screen noise)
#define MAXC 6            // max rival candidates per flagged token
#define NSLOT 512         // recheck flag capacity

typedef float f32x4 __attribute__((ext_vector_type(4)));
typedef short bf16x8 __attribute__((ext_vector_type(8)));
typedef float float4v __attribute__((ext_vector_type(4)));
typedef unsigned short u16x4 __attribute__((ext_vector_type(4)));
typedef unsigned short u16x8 __attribute__((ext_vector_type(8)));

// ---------------------------------------------------------------------------
__device__ __forceinline__ unsigned fkey(float v) {
  unsigned u = __float_as_uint(v);
  return (u & 0x80000000u) ? ~u : (u | 0x80000000u);
}
__device__ __forceinline__ float fdec(unsigned k) {
  unsigned u = (k & 0x80000000u) ? (k & 0x7FFFFFFFu) : ~k;
  return __uint_as_float(u);
}
__device__ __forceinline__ unsigned short bf16_rn(float f) {
  unsigned u = __float_as_uint(f);
  u += 0x7FFFu + ((u >> 16) & 1u);
  return (unsigned short)(u >> 16);
}
__device__ __forceinline__ float bf16_tof(unsigned short h) {
  return __uint_as_float(((unsigned)h) << 16);
}

// ---------------------------------------------------------------------------
// Pre-split kernels: f32 -> bf16 hi (+ lo residual), vectorized x4.
// ---------------------------------------------------------------------------
__global__ __launch_bounds__(256) void split2_kernel(
    const float* __restrict__ src, unsigned short* __restrict__ hi,
    unsigned short* __restrict__ lo, long long n4) {
  long long i = (long long)blockIdx.x * 256 + threadIdx.x;
  long long stride = (long long)gridDim.x * 256;
  for (; i < n4; i += stride) {
    float4v v = ((const float4v*)src)[i];
    u16x4 h, l;
#pragma unroll
    for (int j = 0; j < 4; ++j) {
      unsigned short hh = bf16_rn(v[j]);
      h[j] = hh;
      l[j] = bf16_rn(v[j] - bf16_tof(hh));
    }
    ((u16x4*)hi)[i] = h;
    ((u16x4*)lo)[i] = l;
  }
}

__global__ __launch_bounds__(256) void split1_kernel(
    const float* __restrict__ src, unsigned short* __restrict__ hi, long long n4) {
  long long i = (long long)blockIdx.x * 256 + threadIdx.x;
  long long stride = (long long)gridDim.x * 256;
  for (; i < n4; i += stride) {
    float4v v = ((const float4v*)src)[i];
    u16x4 h;
#pragma unroll
    for (int j = 0; j < 4; ++j) h[j] = bf16_rn(v[j]);
    ((u16x4*)hi)[i] = h;
  }
}

// ---------------------------------------------------------------------------
// q GEMM (pre-split inputs, 256 threads, 4 waves 2Mx2N, 128x64 tile, BK=32):
// q[b,m,n] = sum_t Wq[m,t]*x[b,t,n] + bq[m]; writes qh/ql (bf16 split).
// Grid 8x8x8 = 512 blocks -> 2 blocks/CU (latency hiding across barriers).
// ---------------------------------------------------------------------------
__global__ __launch_bounds__(256) void mfma_q(
    const unsigned short* __restrict__ Wqh, const unsigned short* __restrict__ Wql,
    const unsigned short* __restrict__ xh, const unsigned short* __restrict__ xl,
    const float* __restrict__ bq,
    unsigned short* __restrict__ qh, unsigned short* __restrict__ ql) {
  __shared__ unsigned short Ah[128][40], Al[128][40], Bh[64][40], Bl[64][40];

  const int b = blockIdx.z;
  const unsigned short* xhb = xh + (size_t)b * TT * CC;
  const unsigned short* xlb = xl + (size_t)b * TT * CC;
  const int m0 = blockIdx.y * 128;  // nodes
  const int n0 = blockIdx.x * 64;   // c
  const int tid = threadIdx.x;
  const int l = tid & 63;
  const int wid = tid >> 6;        // 4 waves
  const int wy = wid >> 1;         // 0..1 -> 64-row band
  const int wx = wid & 1;          // 0..1 -> 32-col band
  const int lrow = l & 15, lkb = (l >> 4) * 8;
  const int nn = tid & 63, kq = tid >> 6;  // B transpose assignment (64 x 4)

  f32x4 acc[4][2] = {};

  for (int k0 = 0; k0 < TT; k0 += 32) {
    // A tile: 128 rows x 32 k, pure u16x8 copies (2 chunks/thread).
#pragma unroll
    for (int p = 0; p < 2; ++p) {
      int idx = tid + p * 256;
      int ar = idx >> 2, ack = (idx & 3) * 8;
      *(u16x8*)&Ah[ar][ack] = *(const u16x8*)(Wqh + (size_t)(m0 + ar) * TT + k0 + ack);
      *(u16x8*)&Al[ar][ack] = *(const u16x8*)(Wql + (size_t)(m0 + ar) * TT + k0 + ack);
    }
    // B tile: transpose staging from x [k][n] -> Bh[n][k].
    {
      u16x8 hv, lv;
#pragma unroll
      for (int j = 0; j < 8; ++j) {
        size_t gi = (size_t)(k0 + kq * 8 + j) * CC + n0 + nn;
        hv[j] = xhb[gi];
        lv[j] = xlb[gi];
      }
      *(u16x8*)&Bh[nn][kq * 8] = hv;
      *(u16x8*)&Bl[nn][kq * 8] = lv;
    }
    __syncthreads();

    bf16x8 ah[4], al[4], bh[2], bl[2];
#pragma unroll
    for (int mf = 0; mf < 4; ++mf) {
      ah[mf] = *(const bf16x8*)&Ah[wy * 64 + mf * 16 + lrow][lkb];
      al[mf] = *(const bf16x8*)&Al[wy * 64 + mf * 16 + lrow][lkb];
    }
#pragma unroll
    for (int nf = 0; nf < 2; ++nf) {
      bh[nf] = *(const bf16x8*)&Bh[wx * 32 + nf * 16 + lrow][lkb];
      bl[nf] = *(const bf16x8*)&Bl[wx * 32 + nf * 16 + lrow][lkb];
    }
#pragma unroll
    for (int mf = 0; mf < 4; ++mf)
#pragma unroll
      for (int nf = 0; nf < 2; ++nf) {
        acc[mf][nf] =
            __builtin_amdgcn_mfma_f32_16x16x32_bf16(ah[mf], bh[nf], acc[mf][nf], 0, 0, 0);
        acc[mf][nf] =
            __builtin_amdgcn_mfma_f32_16x16x32_bf16(ah[mf], bl[nf], acc[mf][nf], 0, 0, 0);
        acc[mf][nf] =
            __builtin_amdgcn_mfma_f32_16x16x32_bf16(al[mf], bh[nf], acc[mf][nf], 0, 0, 0);
      }
    __syncthreads();
  }

#pragma unroll
  for (int mf = 0; mf < 4; ++mf)
#pragma unroll
    for (int r = 0; r < 4; ++r) {
      int m = m0 + wy * 64 + mf * 16 + (l >> 4) * 4 + r;
      float bias = bq[m];
#pragma unroll
      for (int nf = 0; nf < 2; ++nf) {
        int n = n0 + wx * 32 + nf * 16 + lrow;
        float v = acc[mf][nf][r] + bias;
        size_t off = ((size_t)b * NNODE + m) * CC + n;
        unsigned short h = bf16_rn(v);
        qh[off] = h;
        ql[off] = bf16_rn(v - bf16_tof(h));
      }
    }
}

// ---------------------------------------------------------------------------
// Fused k (split) + v (plain) projection from pre-split inputs (256 threads).
// ---------------------------------------------------------------------------
__global__ __launch_bounds__(256) void mfma_kv_pre(
    const unsigned short* __restrict__ xh, const unsigned short* __restrict__ xl,
    const unsigned short* __restrict__ Wkh, const unsigned short* __restrict__ Wkl,
    const unsigned short* __restrict__ Wvh,
    unsigned short* __restrict__ kh, unsigned short* __restrict__ kl,
    unsigned short* __restrict__ vout) {
  __shared__ unsigned short Ah[128][40], Al[128][40], Bkh[128][40], Bkl[128][40],
      Bvh[128][40];

  const int b = blockIdx.z;
  const unsigned short* xhb = xh + (size_t)b * TT * CC;
  const unsigned short* xlb = xl + (size_t)b * TT * CC;
  const int m0 = blockIdx.y * 128;  // tokens
  const int n0 = blockIdx.x * 128;  // out dim
  const int tid = threadIdx.x;
  const int l = tid & 63;
  const int wid = tid >> 6;
  const int wy = wid >> 1, wx = wid & 1;
  const int lrow = l & 15, lkb = (l >> 4) * 8;

  f32x4 acck[4][4] = {}, accv[4][4] = {};

  for (int k0 = 0; k0 < CC; k0 += 32) {
#pragma unroll
    for (int p = 0; p < 2; ++p) {
      int idx = tid + p * 256;
      int r = idx >> 2, ck = (idx & 3) * 8;
      *(u16x8*)&Ah[r][ck] = *(const u16x8*)(xhb + (size_t)(m0 + r) * CC + k0 + ck);
      *(u16x8*)&Al[r][ck] = *(const u16x8*)(xlb + (size_t)(m0 + r) * CC + k0 + ck);
      *(u16x8*)&Bkh[r][ck] = *(const u16x8*)(Wkh + (size_t)(n0 + r) * CC + k0 + ck);
      *(u16x8*)&Bkl[r][ck] = *(const u16x8*)(Wkl + (size_t)(n0 + r) * CC + k0 + ck);
      *(u16x8*)&Bvh[r][ck] = *(const u16x8*)(Wvh + (size_t)(n0 + r) * CC + k0 + ck);
    }
    __syncthreads();

    bf16x8 ah[4], al[4], bkh4[4], bkl4[4], bvh4[4];
#pragma unroll
    for (int mf = 0; mf < 4; ++mf) {
      ah[mf] = *(const bf16x8*)&Ah[wy * 64 + mf * 16 + lrow][lkb];
      al[mf] = *(const bf16x8*)&Al[wy * 64 + mf * 16 + lrow][lkb];
    }
#pragma unroll
    for (int nf = 0; nf < 4; ++nf) {
      bkh4[nf] = *(const bf16x8*)&Bkh[wx * 64 + nf * 16 + lrow][lkb];
      bkl4[nf] = *(const bf16x8*)&Bkl[wx * 64 + nf * 16 + lrow][lkb];
      bvh4[nf] = *(const bf16x8*)&Bvh[wx * 64 + nf * 16 + lrow][lkb];
    }
#pragma unroll
    for (int mf = 0; mf < 4; ++mf)
#pragma unroll
      for (int nf = 0; nf < 4; ++nf) {
        acck[mf][nf] =
            __builtin_amdgcn_mfma_f32_16x16x32_bf16(ah[mf], bkh4[nf], acck[mf][nf], 0, 0, 0);
        acck[mf][nf] =
            __builtin_amdgcn_mfma_f32_16x16x32_bf16(ah[mf], bkl4[nf], acck[mf][nf], 0, 0, 0);
        acck[mf][nf] =
            __builtin_amdgcn_mfma_f32_16x16x32_bf16(al[mf], bkh4[nf], acck[mf][nf], 0, 0, 0);
        accv[mf][nf] =
            __builtin_amdgcn_mfma_f32_16x16x32_bf16(ah[mf], bvh4[nf], accv[mf][nf], 0, 0, 0);
      }
    __syncthreads();
  }

#pragma unroll
  for (int mf = 0; mf < 4; ++mf)
#pragma unroll
    for (int r = 0; r < 4; ++r) {
      int m = m0 + wy * 64 + mf * 16 + (l >> 4) * 4 + r;
#pragma unroll
      for (int nf = 0; nf < 4; ++nf) {
        int n = n0 + wx * 64 + nf * 16 + lrow;
        size_t off = ((size_t)b * TT + m) * CC + n;
        float kvv = acck[mf][nf][r];
        unsigned short h = bf16_rn(kvv);
        kh[off] = h;
        kl[off] = bf16_rn(kvv - bf16_tof(h));
        vout[off] = bf16_rn(accv[mf][nf][r]);
      }
    }
}

// ---------------------------------------------------------------------------
// sim (pre-split q,k; no store) + per-block per-token top-3 candidates.
// ---------------------------------------------------------------------------
__global__ __launch_bounds__(256) void mfma_sim_pre(
    const unsigned short* __restrict__ qh, const unsigned short* __restrict__ ql,
    const unsigned short* __restrict__ kh, const unsigned short* __restrict__ kl,
    unsigned long long* __restrict__ cand1, unsigned long long* __restrict__ cand2,
    unsigned long long* __restrict__ cand3) {
  __shared__ unsigned short Ah[128][40], Al[128][40], Bh[128][40], Bl[128][40];
  __shared__ unsigned long long c1[128], c2[128], c3[128];

  const int b = blockIdx.z;
  const unsigned short* qhb = qh + (size_t)b * NNODE * CC;
  const unsigned short* qlb = ql + (size_t)b * NNODE * CC;
  const unsigned short* khb = kh + (size_t)b * TT * CC;
  const unsigned short* klb = kl + (size_t)b * TT * CC;
  const int n0 = blockIdx.y * 128;  // nodes
  const int t0 = blockIdx.x * 128;  // tokens
  const int tid = threadIdx.x;
  const int l = tid & 63;
  const int wid = tid >> 6;
  const int wy = wid >> 1, wx = wid & 1;
  const int lrow = l & 15, lkb = (l >> 4) * 8;

  if (tid < 128) { c1[tid] = 0ULL; c2[tid] = 0ULL; c3[tid] = 0ULL; }

  f32x4 acc[4][4] = {};

  for (int k0 = 0; k0 < CC; k0 += 32) {
#pragma unroll
    for (int p = 0; p < 2; ++p) {
      int idx = tid + p * 256;
      int r = idx >> 2, ck = (idx & 3) * 8;
      *(u16x8*)&Ah[r][ck] = *(const u16x8*)(qhb + (size_t)(n0 + r) * CC + k0 + ck);
      *(u16x8*)&Al[r][ck] = *(const u16x8*)(qlb + (size_t)(n0 + r) * CC + k0 + ck);
      *(u16x8*)&Bh[r][ck] = *(const u16x8*)(khb + (size_t)(t0 + r) * CC + k0 + ck);
      *(u16x8*)&Bl[r][ck] = *(const u16x8*)(klb + (size_t)(t0 + r) * CC + k0 + ck);
    }
    __syncthreads();

    bf16x8 ah[4], al[4], bh[4], bl[4];
#pragma unroll
    for (int mf = 0; mf < 4; ++mf) {
      ah[mf] = *(const bf16x8*)&Ah[wy * 64 + mf * 16 + lrow][lkb];
      al[mf] = *(const bf16x8*)&Al[wy * 64 + mf * 16 + lrow][lkb];
    }
#pragma unroll
    for (int nf = 0; nf < 4; ++nf) {
      bh[nf] = *(const bf16x8*)&Bh[wx * 64 + nf * 16 + lrow][lkb];
      bl[nf] = *(const bf16x8*)&Bl[wx * 64 + nf * 16 + lrow][lkb];
    }
#pragma unroll
    for (int mf = 0; mf < 4; ++mf)
#pragma unroll
      for (int nf = 0; nf < 4; ++nf) {
        acc[mf][nf] =
            __builtin_amdgcn_mfma_f32_16x16x32_bf16(ah[mf], bh[nf], acc[mf][nf], 0, 0, 0);
        acc[mf][nf] =
            __builtin_amdgcn_mfma_f32_16x16x32_bf16(ah[mf], bl[nf], acc[mf][nf], 0, 0, 0);
        acc[mf][nf] =
            __builtin_amdgcn_mfma_f32_16x16x32_bf16(al[mf], bh[nf], acc[mf][nf], 0, 0, 0);
      }
    __syncthreads();
  }

  const float scl = 0.04419417382415922f;
#pragma unroll
  for (int nf = 0; nf < 4; ++nf) {
    int tcol = wx * 64 + nf * 16 + lrow;
    unsigned long long m = 0ULL;
#pragma unroll
    for (int mf = 0; mf < 4; ++mf)
#pragma unroll
      for (int r = 0; r < 4; ++r) {
        unsigned node = (unsigned)(n0 + wy * 64 + mf * 16 + (l >> 4) * 4 + r);
        unsigned long long pk =
            ((unsigned long long)fkey(acc[mf][nf][r] * scl) << 32) | node;
        if (pk > m) m = pk;
      }
    atomicMax(&c1[tcol], m);
  }
  __syncthreads();
#pragma unroll
  for (int nf = 0; nf < 4; ++nf) {
    int tcol = wx * 64 + nf * 16 + lrow;
    unsigned w1 = (unsigned)c1[tcol];
    unsigned long long m = 0ULL;
#pragma unroll
    for (int mf = 0; mf < 4; ++mf)
#pragma unroll
      for (int r = 0; r < 4; ++r) {
        unsigned node = (unsigned)(n0 + wy * 64 + mf * 16 + (l >> 4) * 4 + r);
        if (node == w1) continue;
        unsigned long long pk =
            ((unsigned long long)fkey(acc[mf][nf][r] * scl) << 32) | node;
        if (pk > m) m = pk;
      }
    if (m) atomicMax(&c2[tcol], m);
  }
  __syncthreads();
#pragma unroll
  for (int nf = 0; nf < 4; ++nf) {
    int tcol = wx * 64 + nf * 16 + lrow;
    unsigned w1 = (unsigned)c1[tcol];
    unsigned w2 = (unsigned)c2[tcol];
    unsigned long long m = 0ULL;
#pragma unroll
    for (int mf = 0; mf < 4; ++mf)
#pragma unroll
      for (int r = 0; r < 4; ++r) {
        unsigned node = (unsigned)(n0 + wy * 64 + mf * 16 + (l >> 4) * 4 + r);
        if (node == w1 || node == w2) continue;
        unsigned long long pk =
            ((unsigned long long)fkey(acc[mf][nf][r] * scl) << 32) | node;
        if (pk > m) m = pk;
      }
    if (m) atomicMax(&c3[tcol], m);
  }
  __syncthreads();
  if (tid < 128) {
    size_t base = ((size_t)b * TT + (t0 + tid)) * 8 + blockIdx.y;
    cand1[base] = c1[tid];
    cand2[base] = c2[tid];
    cand3[base] = c3[tid];
  }
}

// ---------------------------------------------------------------------------
// Wout GEMM (f32 inputs, plain bf16 MFMA, 256 threads, 128x64 tile):
// out[m,n] = sum_c out0[m,c]*Wout[n,c] + bout[n], M flattened = BB*NNODE.
// Grid 8 x 64 = 512 blocks -> 2 blocks/CU.
// ---------------------------------------------------------------------------
__global__ __launch_bounds__(256) void mfma_wout(
    const float* __restrict__ A, const float* __restrict__ Bm,
    float* __restrict__ Cp, const float* __restrict__ bias) {
  __shared__ unsigned short Ah[128][40], Bh[64][40];
  const int m0 = blockIdx.y * 128;
  const int n0 = blockIdx.x * 64;
  const int tid = threadIdx.x;
  const int l = tid & 63;
  const int wid = tid >> 6;
  const int wy = wid >> 1, wx = wid & 1;
  const int lrow = l & 15, lkb = (l >> 4) * 8;

  f32x4 acc[4][2] = {};

  for (int k0 = 0; k0 < CC; k0 += 32) {
#pragma unroll
    for (int p = 0; p < 4; ++p) {
      int idx = tid + p * 256;
      int r = idx >> 3, c = (idx & 7) * 4;
      float4v va = *(const float4v*)(A + (size_t)(m0 + r) * CC + k0 + c);
#pragma unroll
      for (int i = 0; i < 4; ++i) Ah[r][c + i] = bf16_rn(va[i]);
    }
#pragma unroll
    for (int p = 0; p < 2; ++p) {
      int idx = tid + p * 256;
      int r = idx >> 3, c = (idx & 7) * 4;
      if (r < 64) {
        float4v vb = *(const float4v*)(Bm + (size_t)(n0 + r) * CC + k0 + c);
#pragma unroll
        for (int i = 0; i < 4; ++i) Bh[r][c + i] = bf16_rn(vb[i]);
      }
    }
    __syncthreads();

    bf16x8 ah[4], bh[2];
#pragma unroll
    for (int mf = 0; mf < 4; ++mf)
      ah[mf] = *(const bf16x8*)&Ah[wy * 64 + mf * 16 + lrow][lkb];
#pragma unroll
    for (int nf = 0; nf < 2; ++nf)
      bh[nf] = *(const bf16x8*)&Bh[wx * 32 + nf * 16 + lrow][lkb];
#pragma unroll
    for (int mf = 0; mf < 4; ++mf)
#pragma unroll
      for (int nf = 0; nf < 2; ++nf)
        acc[mf][nf] =
            __builtin_amdgcn_mfma_f32_16x16x32_bf16(ah[mf], bh[nf], acc[mf][nf], 0, 0, 0);
    __syncthreads();
  }

#pragma unroll
  for (int mf = 0; mf < 4; ++mf)
#pragma unroll
    for (int r = 0; r < 4; ++r) {
      int m = m0 + wy * 64 + mf * 16 + (l >> 4) * 4 + r;
#pragma unroll
      for (int nf = 0; nf < 2; ++nf) {
        int n = n0 + wx * 32 + nf * 16 + lrow;
        Cp[(size_t)m * CC + n] = acc[mf][nf][r] + bias[n];
      }
    }
}

__global__ __launch_bounds__(256) void fill_zero(unsigned* __restrict__ p, long long n) {
  long long i = (long long)blockIdx.x * 256 + threadIdx.x;
  long long stride = (long long)gridDim.x * 256;
  for (; i < n; i += stride) p[i] = 0u;
}

// 32x32 tile transpose: dst[c][r] = src[r][c].
__global__ __launch_bounds__(256) void transpose_kernel(
    const float* __restrict__ src, float* __restrict__ dst, int R, int C) {
  __shared__ float tile[32][33];
  int r0 = blockIdx.y * 32, c0 = blockIdx.x * 32;
  int tx = threadIdx.x & 31, ty = threadIdx.x >> 5;  // 32 x 8
#pragma unroll
  for (int i = 0; i < 4; ++i)
    tile[ty + i * 8][tx] = src[(size_t)(r0 + ty + i * 8) * C + c0 + tx];
  __syncthreads();
#pragma unroll
  for (int i = 0; i < 4; ++i)
    dst[(size_t)(c0 + ty + i * 8) * R + r0 + tx] = tile[tx][ty + i * 8];
}

// ---------------------------------------------------------------------------
// Merge 8x(top-3) -> global top1 + rivals within GAP_MARGIN -> FLAT flag list.
// ---------------------------------------------------------------------------
__global__ __launch_bounds__(256) void merge_flag_kernel(
    const unsigned long long* __restrict__ cand1,
    const unsigned long long* __restrict__ cand2,
    const unsigned long long* __restrict__ cand3,
    unsigned long long* __restrict__ amaxIdx,
    unsigned* __restrict__ gcount, unsigned* __restrict__ gflag,
    unsigned* __restrict__ clist) {
  int bt = blockIdx.x * 256 + threadIdx.x;  // [0, B*T)
  unsigned long long best = 0ULL;
#pragma unroll
  for (int nb = 0; nb < 8; ++nb) {
    unsigned long long v = cand1[(size_t)bt * 8 + nb];
    if (v > best) best = v;
  }
  amaxIdx[bt] = best;
  float v1 = fdec((unsigned)(best >> 32));
  float thr = v1 - GAP_MARGIN;
  unsigned bestnode = (unsigned)best;

  unsigned nodes[MAXC];
  int cnt = 0;
#pragma unroll
  for (int nb = 0; nb < 8; ++nb) {
    unsigned long long cs[3] = {cand1[(size_t)bt * 8 + nb], cand2[(size_t)bt * 8 + nb],
                                cand3[(size_t)bt * 8 + nb]};
#pragma unroll
    for (int s = 0; s < 3; ++s) {
      float v = fdec((unsigned)(cs[s] >> 32));
      unsigned nd = (unsigned)cs[s];
      if (v >= thr && nd != bestnode && cnt < MAXC) nodes[cnt++] = nd;
    }
  }
  if (cnt > 0) {
    unsigned p = atomicAdd(gcount, 1u);
    if (p < NSLOT) {
      gflag[p] = (unsigned)bt;
      clist[(size_t)bt * 8] = (unsigned)(cnt + 1);
      clist[(size_t)bt * 8 + 1] = bestnode;
      for (int i = 0; i < cnt; ++i) clist[(size_t)bt * 8 + 2 + i] = nodes[i];
    }
  }
}

// ---------------------------------------------------------------------------
// Recheck phase A: k64[fi][d] = sum_c x_t[c] * Wk[d][c]  (f64, exact).
// ---------------------------------------------------------------------------
__global__ __launch_bounds__(256) void recheck_k64(
    const float* __restrict__ x, const float* __restrict__ WkT,
    const unsigned* __restrict__ gcount, const unsigned* __restrict__ gflag,
    double* __restrict__ k64g) {
  __shared__ float xs[CC];
  __shared__ double kpart[64][4];

  const unsigned cnt = min(*gcount, (unsigned)NSLOT);
  const int slot = blockIdx.x >> 3;
  const int dchunk = blockIdx.x & 7;
  if ((unsigned)slot >= cnt) return;
  const int tid = threadIdx.x;

  unsigned bt = gflag[slot];
  int b = bt >> 11, t = bt & (TT - 1);
  const float* xr = x + ((size_t)b * TT + t) * CC;
  xs[tid] = xr[tid];
  xs[tid + 256] = xr[tid + 256];
  __syncthreads();

  const int d = dchunk * 64 + (tid & 63);
  const int part = tid >> 6;
  const int cbase = part * 128;
  double a0 = 0.0, a1 = 0.0;
#pragma unroll 8
  for (int i = 0; i < 64; ++i) {
    int c = cbase + 2 * i;
    a0 = fma((double)WkT[(size_t)c * CC + d], (double)xs[c], a0);
    a1 = fma((double)WkT[(size_t)(c + 1) * CC + d], (double)xs[c + 1], a1);
  }
  kpart[tid & 63][part] = a0 + a1;
  __syncthreads();
  if (tid < 64) {
    double s = (kpart[tid][0] + kpart[tid][1]) + (kpart[tid][2] + kpart[tid][3]);
    k64g[(size_t)slot * CC + dchunk * 64 + tid] = s;
  }
}

// ---------------------------------------------------------------------------
// Recheck phase B: z[fi][t'] = sum_c x[t'][c] * k64[fi][c]  (f64 acc, f32 out).
// ---------------------------------------------------------------------------
__global__ __launch_bounds__(256) void recheck_z(
    const float* __restrict__ x, const unsigned* __restrict__ gcount,
    const unsigned* __restrict__ gflag, const double* __restrict__ k64g,
    float* __restrict__ zg) {
  __shared__ float tile[64][129];
  __shared__ double k64l[CC];
  __shared__ double zp[64][4];

  const unsigned cnt = min(*gcount, (unsigned)NSLOT);
  const int slot = blockIdx.x >> 5;
  const int tchunk = blockIdx.x & 31;
  if ((unsigned)slot >= cnt) return;
  const int tid = threadIdx.x;

  unsigned bt = gflag[slot];
  int b = bt >> 11;
  const float* xb = x + (size_t)b * TT * CC;
  const int tok0 = tchunk * 64;

  k64l[tid] = k64g[(size_t)slot * CC + tid];
  k64l[tid + 256] = k64g[(size_t)slot * CC + tid + 256];

  const int tok = tid >> 2;
  const int part = tid & 3;
  double z0 = 0.0, z1 = 0.0;

  for (int p = 0; p < 4; ++p) {
    __syncthreads();
    int c0 = p * 128;
#pragma unroll
    for (int j = 0; j < 32; ++j) {
      int lin = j * 256 + tid;
      int r = lin >> 7, col = lin & 127;
      tile[r][col] = xb[(size_t)(tok0 + r) * CC + c0 + col];
    }
    __syncthreads();
#pragma unroll
    for (int i = 0; i < 16; ++i) {
      int cl = part * 32 + 2 * i;
      z0 = fma((double)tile[tok][cl], k64l[c0 + cl], z0);
      z1 = fma((double)tile[tok][cl + 1], k64l[c0 + cl + 1], z1);
    }
  }
  zp[tok][part] = z0 + z1;
  __syncthreads();
  if (tid < 64) {
    double z = (zp[tid][0] + zp[tid][1]) + (zp[tid][2] + zp[tid][3]);
    zg[(size_t)slot * TT + tok0 + tid] = (float)z;
  }
}

// ---------------------------------------------------------------------------
// Recheck phase C: sim64(n) = Wq[n,:].z + bq[n]*sum(k64); argmax candidates.
// ---------------------------------------------------------------------------
__global__ __launch_bounds__(256) void recheck_cand(
    const float* __restrict__ Wq, const float* __restrict__ bq,
    const unsigned* __restrict__ gcount, const unsigned* __restrict__ gflag,
    const unsigned* __restrict__ clist, const double* __restrict__ k64g,
    const float* __restrict__ zg, unsigned long long* __restrict__ amaxIdx) {
  __shared__ double red[4];
  __shared__ double ssumS;

  const unsigned cnt = min(*gcount, (unsigned)NSLOT);
  const int slot = blockIdx.x;
  if ((unsigned)slot >= cnt) return;
  const int tid = threadIdx.x;

  unsigned bt = gflag[slot];

  double ps = k64g[(size_t)slot * CC + tid] + k64g[(size_t)slot * CC + tid + 256];
#pragma unroll
  for (int off = 32; off > 0; off >>= 1) ps += __shfl_down(ps, off, 64);
  if ((tid & 63) == 0) red[tid >> 6] = ps;
  __syncthreads();
  if (tid == 0) ssumS = (red[0] + red[1]) + (red[2] + red[3]);
  __syncthreads();
  const double ssum = ssumS;

  const double scl = 0.04419417382415922;
  unsigned ncand = clist[(size_t)bt * 8];
  unsigned long long bestpk = 0ULL;
  double bestv = -1e300;
  for (unsigned ci = 0; ci < ncand; ++ci) {
    unsigned n = clist[(size_t)bt * 8 + 1 + ci];
    const float* wq = Wq + (size_t)n * TT;
    const float* zr = zg + (size_t)slot * TT;
    double a = 0.0;
#pragma unroll
    for (int i = 0; i < TT / 256; ++i) {
      int tp = tid + i * 256;
      a = fma((double)wq[tp], (double)zr[tp], a);
    }
#pragma unroll
    for (int off = 32; off > 0; off >>= 1) a += __shfl_down(a, off, 64);
    if ((tid & 63) == 0) red[tid >> 6] = a;
    __syncthreads();
    double s = ((red[0] + red[1]) + (red[2] + red[3])) + (double)bq[n] * ssum;
    if (s > bestv) {
      bestv = s;
      bestpk = ((unsigned long long)fkey((float)(s * scl)) << 32) | n;
    }
    __syncthreads();
  }
  if (tid == 0) amaxIdx[bt] = bestpk;
}

__global__ __launch_bounds__(256) void node_max_kernel(
    const unsigned long long* __restrict__ amaxIdx, unsigned* __restrict__ Mpack) {
  int i = blockIdx.x * 256 + threadIdx.x;
  unsigned long long pk = amaxIdx[i];
  int b = i >> 11;
  unsigned w = (unsigned)pk;
  atomicMax(&Mpack[b * NNODE + w], (unsigned)(pk >> 32));
}

__global__ __launch_bounds__(256) void node_denom_kernel(
    const unsigned long long* __restrict__ amaxIdx, const unsigned* __restrict__ Mpack,
    float* __restrict__ D, float* __restrict__ att_val) {
  int i = blockIdx.x * 256 + threadIdx.x;
  unsigned long long pk = amaxIdx[i];
  int b = i >> 11;
  unsigned w = (unsigned)pk;
  float amaxf = fdec((unsigned)(pk >> 32));
  float Mf = fdec(Mpack[b * NNODE + w]);
  float e = expf(amaxf - Mf);
  att_val[i] = e;
  atomicAdd(&D[b * NNODE + w], e);
}

__global__ __launch_bounds__(256) void att_write_kernel(
    const unsigned long long* __restrict__ amaxIdx, const float* __restrict__ D,
    float* __restrict__ att_val, float* __restrict__ att_out) {
  int i = blockIdx.x * 256 + threadIdx.x;
  unsigned long long pk = amaxIdx[i];
  int b = i >> 11;
  int t = i & (TT - 1);
  unsigned w = (unsigned)pk;
  float a = att_val[i] / D[b * NNODE + w];
  att_val[i] = a;
  att_out[((size_t)b * NNODE + w) * TT + t] = a;
}

__global__ __launch_bounds__(256) void pv_scatter_kernel(
    const unsigned long long* __restrict__ amaxIdx, const float* __restrict__ att_val,
    const unsigned short* __restrict__ v, float* __restrict__ out0) {
  int bt = blockIdx.x;  // [0, B*T)
  int b = bt >> 11;
  float a = att_val[bt];
  unsigned w = (unsigned)amaxIdx[bt];
  const unsigned short* vr = v + (size_t)bt * CC;
  float* orow = out0 + ((size_t)b * NNODE + w) * CC;
  for (int c = threadIdx.x; c < CC; c += 256)
    atomicAdd(&orow[c], a * bf16_tof(vr[c]));
}

extern "C" void kernel_launch(void* const* d_in, const int* in_sizes, int n_in,
                              void* d_out, int out_size, void* d_ws, size_t ws_size,
                              hipStream_t stream) {
  const float* x = (const float*)d_in[0];     // [B,T,C]  f32
  const float* Wq = (const float*)d_in[1];    // [N,T]
  const float* bq = (const float*)d_in[2];    // [N]
  const float* Wk = (const float*)d_in[3];    // [C,C]
  const float* Wv = (const float*)d_in[4];    // [C,C]
  const float* Wout = (const float*)d_in[5];  // [C,C]
  const float* bout = (const float*)d_in[6];  // [C]

  float* out = (float*)d_out;                      // [B,N,C] f32
  float* att_out = out + (size_t)BB * NNODE * CC;  // [B,N,T] f32

  // Workspace layout: ~111.5 MB total. R = xh/xl region reused post-kv.
  const size_t BNC = (size_t)BB * NNODE * CC;  // 4,194,304
  const size_t BTC = (size_t)BB * TT * CC;     // 8,388,608
  const size_t NT = (size_t)NNODE * TT;        // 2,097,152
  const size_t CC2 = (size_t)CC * CC;          // 262,144
  const size_t BT = (size_t)BB * TT;           // 16,384

  unsigned short* qh = (unsigned short*)d_ws;
  unsigned short* ql = qh + BNC;
  unsigned short* kh = ql + BNC;
  unsigned short* kl = kh + BTC;
  unsigned short* vbuf = kl + BTC;
  unsigned short* Wqh = vbuf + BTC;
  unsigned short* Wql = Wqh + NT;
  unsigned short* Wkh = Wql + NT;
  unsigned short* Wkl = Wkh + CC2;
  unsigned short* Wvh = Wkl + CC2;
  unsigned short* xh = Wvh + CC2;
  unsigned short* xl = xh + BTC;
  unsigned long long* amaxIdx = (unsigned long long*)(xl + BTC);
  unsigned* Mpack = (unsigned*)(amaxIdx + BT);
  float* D = (float*)(Mpack + (size_t)BB * NNODE);
  unsigned* gcount = (unsigned*)(D + (size_t)BB * NNODE);
  float* att_val = (float*)(gcount + 16);
  unsigned* gflag = (unsigned*)(att_val + BT);
  unsigned* clist = gflag + BT;
  // Region R overlays xh/xl (33.5 MB; used after kv; sub-ranges disjoint):
  float* out0 = (float*)xh;                                      // 16.8 MB
  unsigned long long* cand1 = (unsigned long long*)(out0 + BNC); // 1 MB x3
  unsigned long long* cand2 = cand1 + BT * 8;
  unsigned long long* cand3 = cand2 + BT * 8;
  float* WkT = (float*)(cand3 + BT * 8);                         // 1 MB
  double* k64g = (double*)(WkT + CC2);                           // 2 MB
  float* zg = (float*)(k64g + (size_t)NSLOT * CC);               // 4 MB

  dim3 blk(256);

  // Pre-split inputs to bf16 hi/lo (one-time; hot loops become pure copies)
  split2_kernel<<<dim3(2048), blk, 0, stream>>>(x, xh, xl, (long long)(BTC / 4));
  split2_kernel<<<dim3(1024), blk, 0, stream>>>(Wq, Wqh, Wql, (long long)(NT / 4));
  split2_kernel<<<dim3(256), blk, 0, stream>>>(Wk, Wkh, Wkl, (long long)(CC2 / 4));
  split1_kernel<<<dim3(256), blk, 0, stream>>>(Wv, Wvh, (long long)(CC2 / 4));

  // Z1: zero Mpack | D | gcount (contiguous)
  fill_zero<<<dim3(64), blk, 0, stream>>>(Mpack, (long long)BB * NNODE * 2 + 16);
  // Z2: zero att region of d_out
  fill_zero<<<dim3(4096), blk, 0, stream>>>((unsigned*)att_out,
                                            (long long)BB * NNODE * TT);

  // q (bf16-split MFMA, pre-split inputs, 128x64 tile -> 2 blocks/CU)
  mfma_q<<<dim3(CC / 64, NNODE / 128, BB), blk, 0, stream>>>(
      Wqh, Wql, xh, xl, bq, qh, ql);

  // fused k (split) + v (plain) -> kh/kl, vbuf   [last use of xh/xl]
  mfma_kv_pre<<<dim3(CC / 128, TT / 128, BB), blk, 0, stream>>>(
      xh, xl, Wkh, Wkl, Wvh, kh, kl, vbuf);

  // WkT (in R; safe after kv)
  transpose_kernel<<<dim3(CC / 32, CC / 32), blk, 0, stream>>>(Wk, WkT, CC, CC);

  // sim + top-3 candidates (pure-copy staging) -> cand1..3 (in R)
  mfma_sim_pre<<<dim3(TT / 128, NNODE / 128, BB), blk, 0, stream>>>(
      qh, ql, kh, kl, cand1, cand2, cand3);

  // merge -> amaxIdx + flat flag list + candidate lists
  merge_flag_kernel<<<dim3(BB * TT / 256), blk, 0, stream>>>(
      cand1, cand2, cand3, amaxIdx, gcount, gflag, clist);

  // exact f64 recheck: 3 phase-parallel kernels
  recheck_k64<<<dim3(NSLOT * 8), blk, 0, stream>>>(x, WkT, gcount, gflag, k64g);
  recheck_z<<<dim3(NSLOT * 32), blk, 0, stream>>>(x, gcount, gflag, k64g, zg);
  recheck_cand<<<dim3(NSLOT), blk, 0, stream>>>(Wq, bq, gcount, gflag, clist,
                                                k64g, zg, amaxIdx);

  // zero out0 (in R, disjoint from cand/WkT/k64g/zg)
  fill_zero<<<dim3(2048), blk, 0, stream>>>((unsigned*)out0, (long long)BB * NNODE * CC);

  node_max_kernel<<<dim3(BB * TT / 256), blk, 0, stream>>>(amaxIdx, Mpack);
  node_denom_kernel<<<dim3(BB * TT / 256), blk, 0, stream>>>(amaxIdx, Mpack, D, att_val);
  att_write_kernel<<<dim3(BB * TT / 256), blk, 0, stream>>>(amaxIdx, D, att_val, att_out);

  // sparse PV scatter: out0[b,w,c] += att * v[b,t,c]
  pv_scatter_kernel<<<dim3(BB * TT), blk, 0, stream>>>(amaxIdx, att_val, vbuf, out0);

  // out = out0 . Wout^T + bout  (plain MFMA, 128x64 tile -> 2 blocks/CU)
  mfma_wout<<<dim3(CC / 64, BB * NNODE / 128), blk, 0, stream>>>(
      out0, Wout, out, bout);
}